// Round 4
// baseline (503.838 us; speedup 1.0000x reference)
//
#include <hip/hip_runtime.h>
#include <hip/hip_bf16.h>

#define N_NODES_C 100000
#define N_EDGES_C 1600000
#define N_BUCK ((N_NODES_C + 255) / 256)   // 391
#define BCAP 4608                          // per-bucket capacity, mean 4092 + 8 sigma
#define PART_NB 160
#define PART_CHUNK ((N_EDGES_C + PART_NB - 1) / PART_NB)  // 10000

#define FB_NODES 64                        // nodes per fused block

typedef __attribute__((ext_vector_type(8))) short          short8;   // 8 bf16
typedef __attribute__((ext_vector_type(4))) float          f32x4;
typedef __attribute__((ext_vector_type(4))) unsigned int   u32x4;
typedef __attribute__((ext_vector_type(4))) unsigned short u16x4;

// ---------------------------------------------------------------------------
__device__ inline float load1v(const void* p, size_t i, int bf) {
    return bf ? __bfloat162float(((const __hip_bfloat16*)p)[i])
              : ((const float*)p)[i];
}
__device__ inline unsigned short f2bf(float f) {
    __hip_bfloat16 h = __float2bfloat16(f);
    return *reinterpret_cast<unsigned short*>(&h);
}
__device__ inline float bf_lo(unsigned u) { return __uint_as_float(u << 16); }
__device__ inline float bf_hi(unsigned u) { return __uint_as_float(u & 0xffff0000u); }
__device__ inline void acc8(float* a, u32x4 r) {
    a[0] += bf_lo(r.x); a[1] += bf_hi(r.x);
    a[2] += bf_lo(r.y); a[3] += bf_hi(r.y);
    a[4] += bf_lo(r.z); a[5] += bf_hi(r.z);
    a[6] += bf_lo(r.w); a[7] += bf_hi(r.w);
}
// X-tile byte address: row*512 + swizzled 16B chunk (XOR row&7) + sub-offset.
__device__ inline int xaddr(int l, int byteCol) {
    return l * 512 + ((((byteCol >> 4) ^ (l & 7)) << 4)) + (byteCol & 15);
}

// ---------------------------------------------------------------------------
// Dtype probe (gflag=1 iff float tensors are bf16) + bucket cursor init.
__global__ void detect_init(const void* __restrict__ feats, int* __restrict__ gflag,
                            int* __restrict__ bcur) {
    const unsigned short* u = (const unsigned short*)feats;
    int bad = 0;
    for (int i = threadIdx.x; i < 2048; i += 64) {
        unsigned e = (u[i] >> 7) & 0xFF;
        if (e >= 0xC0) bad++;
    }
#pragma unroll
    for (int off = 32; off > 0; off >>= 1) bad += __shfl_down(bad, off, 64);
    if (threadIdx.x == 0) *gflag = (bad == 0) ? 1 : 0;
    for (int b = threadIdx.x; b < N_BUCK; b += 64) bcur[b] = b * BCAP;
}

// ---------------------------------------------------------------------------
// Privatized two-pass partition into FIXED-CAP bucket slots.
__global__ __launch_bounds__(256) void partition2(
        const int* __restrict__ src, const int* __restrict__ dst,
        int* __restrict__ bcur, unsigned* __restrict__ pairs) {
    __shared__ int cnt[N_BUCK];
    __shared__ int lbase[N_BUCK];
    int tid = threadIdx.x;
    int e0 = blockIdx.x * PART_CHUNK;
    int e1 = min(e0 + PART_CHUNK, N_EDGES_C);
    for (int i = tid; i < N_BUCK; i += 256) cnt[i] = 0;
    __syncthreads();
    for (int e = e0 + tid; e < e1; e += 256)
        atomicAdd(&cnt[dst[e] >> 8], 1);
    __syncthreads();
    for (int i = tid; i < N_BUCK; i += 256) {
        int c = cnt[i];
        lbase[i] = c ? atomicAdd(&bcur[i], c) : 0;
        cnt[i] = 0;                       // reuse as local cursor
    }
    __syncthreads();
    for (int e = e0 + tid; e < e1; e += 256) {
        int s = src[e], d = dst[e];
        int bk = d >> 8;
        int pos = lbase[bk] + atomicAdd(&cnt[bk], 1);
        pairs[pos] = ((unsigned)(d & 255) << 17) | (unsigned)s;
    }
}

// Compact csr offsets from bucket fill levels (LDS-staged)
__global__ void mkboff_kernel(const int* __restrict__ bcur, int* __restrict__ boff) {
    __shared__ int c[N_BUCK];
    int tid = threadIdx.x;
    for (int i = tid; i < N_BUCK; i += 64) c[i] = bcur[i] - i * BCAP;
    __syncthreads();
    if (tid == 0) {
        int run = 0;
        for (int b = 0; b < N_BUCK; ++b) { int t = c[b]; c[b] = run; run += t; }
        boff[N_BUCK] = run;
    }
    __syncthreads();
    for (int i = tid; i < N_BUCK; i += 64) boff[i] = c[i];
}

// One block per bucket: per-node count + LDS scan -> row_start/deg, then emit
// csr (compact layout at boff) from the padded pairs window at b*BCAP.
__global__ __launch_bounds__(256) void bucket_fill(
        const unsigned* __restrict__ pairs, const int* __restrict__ boff,
        int* __restrict__ csr, int* __restrict__ row_start, int* __restrict__ deg) {
    __shared__ int cnt[256], sd[256], lcur[256];
    int b = blockIdx.x, tid = threadIdx.x;
    int pbase = b * BCAP;
    int base = boff[b], count = boff[b + 1] - base;
    cnt[tid] = 0;
    __syncthreads();
    for (int i = tid; i < count; i += 256)
        atomicAdd(&cnt[pairs[pbase + i] >> 17], 1);
    __syncthreads();
    sd[tid] = cnt[tid];
    __syncthreads();
    for (int st = 1; st < 256; st <<= 1) {
        int t = (tid >= st) ? sd[tid - st] : 0;
        __syncthreads();
        sd[tid] += t;
        __syncthreads();
    }
    int excl = sd[tid] - cnt[tid];
    int node = b * 256 + tid;
    if (node < N_NODES_C) { row_start[node] = base + excl; deg[node] = cnt[tid]; }
    lcur[tid] = excl;
    __syncthreads();
    for (int i = tid; i < count; i += 256) {
        unsigned p = pairs[pbase + i];
        int pos = base + atomicAdd(&lcur[p >> 17], 1);
        csr[pos] = (int)(p & 0x1FFFFu);
    }
}

// ---------------------------------------------------------------------------
// Weight prep. Wt rows 0..127: L0 (K=256); 128..255: L1 (K=256);
// L2 compact at Wt+65536: 80 rows x K=128 (cols 0..39 = Ws2, 40..79 = Wn2).
__global__ void prep_weights(const void* Ws0, const void* bs0, const void* Wn0, const void* bn0,
                             const void* Ws1, const void* bs1, const void* Wn1, const void* bn1,
                             const void* Ws2, const void* bs2, const void* Wn2, const void* bn2,
                             unsigned short* __restrict__ Wt, float* __restrict__ bcat,
                             const int* __restrict__ gflag) {
    int gb = *gflag;
    int n = blockIdx.x;        // 0..335
    int k = threadIdx.x;       // 0..255
    if (n < 128) {
        float v = (k < 128) ? load1v(Ws0, (size_t)k * 128 + n, gb)
                            : load1v(Wn0, (size_t)(k - 128) * 128 + n, gb);
        Wt[(size_t)n * 256 + k] = f2bf(v);
        if (k == 0) bcat[n] = load1v(bs0, n, gb) + load1v(bn0, n, gb);
    } else if (n < 256) {
        int c = n - 128;
        float v = (k < 128) ? load1v(Ws1, (size_t)k * 128 + c, gb)
                            : load1v(Wn1, (size_t)(k - 128) * 128 + c, gb);
        Wt[(size_t)n * 256 + k] = f2bf(v);
        if (k == 0) bcat[n] = load1v(bs1, c, gb) + load1v(bn1, c, gb);
    } else {
        int c = n - 256;       // 0..79
        if (k < 128) {
            float v = (c < 40) ? load1v(Ws2, (size_t)k * 40 + c, gb)
                               : load1v(Wn2, (size_t)k * 40 + (c - 40), gb);
            Wt[65536 + (size_t)c * 128 + k] = f2bf(v);
        }
        if (k == 0) bcat[n] = (c < 40) ? load1v(bs2, c, gb) + load1v(bn2, c, gb) : 0.0f;
    }
}

// ---------------------------------------------------------------------------
// FUSED layer v2: gather-mean into LDS X-tile [64 rows x 256 cols bf16,
// swizzled] (+self copy), then MFMA h_out = relu+l2norm(X @ W + b).
// W is read DIRECTLY from global in the MFMA loop (64 KB, L1/L2-hot across
// all blocks) -> LDS = 32 KB only -> 4+ blocks/CU, occupancy back in the
// saturated random-read regime (>=45% -> ~3.6 TB/s).
__global__ __launch_bounds__(256, 4) void fused_layer(
        const void* __restrict__ hsrc, int src_stride, int src_mode,
        const int* __restrict__ csr, const int* __restrict__ row_start,
        const int* __restrict__ deg,
        const u32x4* __restrict__ Wg,            // [128][32] 16B chunks
        const float* __restrict__ bias,          // [128]
        unsigned short* __restrict__ hout,       // stride 128 bf16
        int n_nodes, const int* __restrict__ gflag) {
    __shared__ u32x4 xt4[FB_NODES * 32];         // 32 KB X-tile
    char* xt = (char*)xt4;

    int tid = threadIdx.x;
    int wave = tid >> 6, lane = tid & 63;
    int g = lane >> 4, sub = lane & 15;
    int srcLane = lane & 48;                     // g*16
    int bf = (src_mode == 2) ? *gflag : src_mode;
    int nb0 = blockIdx.x * FB_NODES;

    // ---- gather phase: 16 groups x 4 sequential nodes ----
    for (int t = 0; t < 4; ++t) {
        int l = (wave * 4 + g) * 4 + t;          // local node 0..63
        int node = nb0 + l;
        bool valid = node < n_nodes;
        int vnode = valid ? node : (n_nodes - 1);
        int start = row_start[vnode];
        int d = valid ? deg[vnode] : 0;
        const int* cp = csr + start;
        float inv = (d > 0) ? 1.0f / (float)d : 0.0f;

        if (bf) {
            const unsigned short* hb = (const unsigned short*)hsrc;
            float a[8] = {0, 0, 0, 0, 0, 0, 0, 0};
            for (int base = 0; base < d; base += 16) {
                int n16 = min(d - base, 16);
                int idxr = cp[base + ((sub < n16) ? sub : 0)];
                int i = 0;
                for (; i + 8 <= n16; i += 8) {
                    int nb_0 = __shfl(idxr, srcLane + i + 0, 64);
                    int nb_1 = __shfl(idxr, srcLane + i + 1, 64);
                    int nb_2 = __shfl(idxr, srcLane + i + 2, 64);
                    int nb_3 = __shfl(idxr, srcLane + i + 3, 64);
                    int nb_4 = __shfl(idxr, srcLane + i + 4, 64);
                    int nb_5 = __shfl(idxr, srcLane + i + 5, 64);
                    int nb_6 = __shfl(idxr, srcLane + i + 6, 64);
                    int nb_7 = __shfl(idxr, srcLane + i + 7, 64);
                    u32x4 r0 = *(const u32x4*)(hb + (size_t)nb_0 * src_stride + sub * 8);
                    u32x4 r1 = *(const u32x4*)(hb + (size_t)nb_1 * src_stride + sub * 8);
                    u32x4 r2 = *(const u32x4*)(hb + (size_t)nb_2 * src_stride + sub * 8);
                    u32x4 r3 = *(const u32x4*)(hb + (size_t)nb_3 * src_stride + sub * 8);
                    u32x4 r4 = *(const u32x4*)(hb + (size_t)nb_4 * src_stride + sub * 8);
                    u32x4 r5 = *(const u32x4*)(hb + (size_t)nb_5 * src_stride + sub * 8);
                    u32x4 r6 = *(const u32x4*)(hb + (size_t)nb_6 * src_stride + sub * 8);
                    u32x4 r7 = *(const u32x4*)(hb + (size_t)nb_7 * src_stride + sub * 8);
                    acc8(a, r0); acc8(a, r1); acc8(a, r2); acc8(a, r3);
                    acc8(a, r4); acc8(a, r5); acc8(a, r6); acc8(a, r7);
                }
                for (; i + 4 <= n16; i += 4) {
                    int nb_0 = __shfl(idxr, srcLane + i + 0, 64);
                    int nb_1 = __shfl(idxr, srcLane + i + 1, 64);
                    int nb_2 = __shfl(idxr, srcLane + i + 2, 64);
                    int nb_3 = __shfl(idxr, srcLane + i + 3, 64);
                    u32x4 r0 = *(const u32x4*)(hb + (size_t)nb_0 * src_stride + sub * 8);
                    u32x4 r1 = *(const u32x4*)(hb + (size_t)nb_1 * src_stride + sub * 8);
                    u32x4 r2 = *(const u32x4*)(hb + (size_t)nb_2 * src_stride + sub * 8);
                    u32x4 r3 = *(const u32x4*)(hb + (size_t)nb_3 * src_stride + sub * 8);
                    acc8(a, r0); acc8(a, r1); acc8(a, r2); acc8(a, r3);
                }
                for (; i < n16; ++i) {
                    int nb_ = __shfl(idxr, srcLane + i, 64);
                    u32x4 r = *(const u32x4*)(hb + (size_t)nb_ * src_stride + sub * 8);
                    acc8(a, r);
                }
            }
            // mean -> cols 128..255 (chunk 16+sub); self -> cols 0..127 (chunk sub)
            u32x4 o;
            o.x = (unsigned)f2bf(a[0] * inv) | ((unsigned)f2bf(a[1] * inv) << 16);
            o.y = (unsigned)f2bf(a[2] * inv) | ((unsigned)f2bf(a[3] * inv) << 16);
            o.z = (unsigned)f2bf(a[4] * inv) | ((unsigned)f2bf(a[5] * inv) << 16);
            o.w = (unsigned)f2bf(a[6] * inv) | ((unsigned)f2bf(a[7] * inv) << 16);
            *(u32x4*)(xt + xaddr(l, 256 + sub * 16)) = o;
            u32x4 raw = *(const u32x4*)(hb + (size_t)vnode * src_stride + sub * 8);
            *(u32x4*)(xt + xaddr(l, sub * 16)) = raw;
        } else {
            const float* hf = (const float*)hsrc;
            float a[8] = {0, 0, 0, 0, 0, 0, 0, 0};
            for (int base = 0; base < d; base += 16) {
                int n16 = min(d - base, 16);
                int idxr = cp[base + ((sub < n16) ? sub : 0)];
                int i = 0;
                for (; i + 4 <= n16; i += 4) {
                    int nb_0 = __shfl(idxr, srcLane + i + 0, 64);
                    int nb_1 = __shfl(idxr, srcLane + i + 1, 64);
                    int nb_2 = __shfl(idxr, srcLane + i + 2, 64);
                    int nb_3 = __shfl(idxr, srcLane + i + 3, 64);
                    const float* p0 = hf + (size_t)nb_0 * src_stride + sub * 4;
                    const float* p1 = hf + (size_t)nb_1 * src_stride + sub * 4;
                    const float* p2 = hf + (size_t)nb_2 * src_stride + sub * 4;
                    const float* p3 = hf + (size_t)nb_3 * src_stride + sub * 4;
                    f32x4 a0 = *(const f32x4*)p0, b0 = *(const f32x4*)(p0 + 64);
                    f32x4 a1 = *(const f32x4*)p1, b1 = *(const f32x4*)(p1 + 64);
                    f32x4 a2 = *(const f32x4*)p2, b2 = *(const f32x4*)(p2 + 64);
                    f32x4 a3 = *(const f32x4*)p3, b3 = *(const f32x4*)(p3 + 64);
#pragma unroll
                    for (int k = 0; k < 4; ++k) {
                        a[k] += a0[k] + a1[k] + a2[k] + a3[k];
                        a[4 + k] += b0[k] + b1[k] + b2[k] + b3[k];
                    }
                }
                for (; i < n16; ++i) {
                    int nb_ = __shfl(idxr, srcLane + i, 64);
                    const float* p0 = hf + (size_t)nb_ * src_stride + sub * 4;
                    f32x4 a0 = *(const f32x4*)p0, b0 = *(const f32x4*)(p0 + 64);
#pragma unroll
                    for (int k = 0; k < 4; ++k) { a[k] += a0[k]; a[4 + k] += b0[k]; }
                }
            }
            // mean: cols 128+sub*4.. and 128+64+sub*4..  (8B writes)
            u16x4 oa = { f2bf(a[0] * inv), f2bf(a[1] * inv),
                         f2bf(a[2] * inv), f2bf(a[3] * inv) };
            u16x4 ob = { f2bf(a[4] * inv), f2bf(a[5] * inv),
                         f2bf(a[6] * inv), f2bf(a[7] * inv) };
            *(u16x4*)(xt + xaddr(l, 256 + sub * 8)) = oa;
            *(u16x4*)(xt + xaddr(l, 384 + sub * 8)) = ob;
            // self: cols sub*4.. and 64+sub*4..
            const float* sp = hf + (size_t)vnode * src_stride + sub * 4;
            f32x4 ra = *(const f32x4*)sp;
            f32x4 rb = *(const f32x4*)(sp + 64);
            u16x4 sa = { f2bf(ra.x), f2bf(ra.y), f2bf(ra.z), f2bf(ra.w) };
            u16x4 sb = { f2bf(rb.x), f2bf(rb.y), f2bf(rb.z), f2bf(rb.w) };
            *(u16x4*)(xt + xaddr(l, sub * 8)) = sa;
            *(u16x4*)(xt + xaddr(l, 128 + sub * 8)) = sb;
        }
    }
    __syncthreads();

    // ---- MFMA phase: wave handles 16 nodes (lrow = wave*16+sub) ----
    // W fragments straight from global: Wg[ncol*32 + kt*4 + quad], identical
    // chunk layout to the old LDS-staged path (half*16 + kt4*4 + quad).
    int quad = g;                                // lane>>4
    int lrow = wave * 16 + sub;
    int mynode = nb0 + lrow;

    f32x4 acc[8];
#pragma unroll
    for (int ct = 0; ct < 8; ++ct) acc[ct] = (f32x4){0, 0, 0, 0};

#pragma unroll
    for (int kt = 0; kt < 8; ++kt) {
        short8 av = *(const short8*)(xt + xaddr(lrow, quad * 16 + kt * 64));
#pragma unroll
        for (int ct = 0; ct < 8; ++ct) {
            int ncol = ct * 16 + sub;
            union { u32x4 u; short8 s; } cv;
            cv.u = Wg[ncol * 32 + kt * 4 + quad];
            acc[ct] = __builtin_amdgcn_mfma_f32_16x16x32_bf16(cv.s, av, acc[ct], 0, 0, 0);
        }
    }

    float ss = 0.0f;
#pragma unroll
    for (int ct = 0; ct < 8; ++ct) {
        f32x4 b4 = *(const f32x4*)(bias + ct * 16 + quad * 4);
#pragma unroll
        for (int r = 0; r < 4; ++r) {
            float v = acc[ct][r] + b4[r];
            v = fmaxf(v, 0.0f); ss += v * v;
            acc[ct][r] = v;
        }
    }
    ss += __shfl_xor(ss, 16, 64);
    ss += __shfl_xor(ss, 32, 64);
    float scale = 1.0f / fmaxf(sqrtf(ss), 1e-12f);
    if (mynode < n_nodes) {
#pragma unroll
        for (int ct = 0; ct < 8; ++ct) {
            int c0 = ct * 16 + quad * 4;
            u16x4 o = { f2bf(acc[ct][0] * scale), f2bf(acc[ct][1] * scale),
                        f2bf(acc[ct][2] * scale), f2bf(acc[ct][3] * scale) };
            *(u16x4*)(hout + (size_t)mynode * 128 + c0) = o;
        }
    }
}

// ---------------------------------------------------------------------------
// MFMA GEMM (layer 2 only). DUAL: cols 0..39 -> Zbuf (stride 40),
// cols 40..79 -> Ybuf (stride 40).
template <int NCT, int KT, int CHK, bool ACTNORM, bool DUAL>
__global__ __launch_bounds__(256) void mfma_gemm(
        const unsigned short* __restrict__ X, int astride,
        const u32x4* __restrict__ Wg,           // [NCT*16][CHK] 16B chunks
        const float* __restrict__ bias,         // [NCT*16]
        unsigned short* __restrict__ out, int out_stride,
        unsigned short* __restrict__ Ybuf, unsigned short* __restrict__ Zbuf,
        int n_nodes) {
    __shared__ u32x4 ldsW[NCT * 16 * CHK];
    int tid = threadIdx.x;
    for (int c = tid; c < NCT * 16 * CHK; c += 256) {
        int nrow = c / CHK, ch = c % CHK;
        ldsW[nrow * CHK + (ch ^ (nrow & 7))] = Wg[c];
    }
    __syncthreads();

    int wave = tid >> 6, lane = tid & 63;
    int quad = lane >> 4, sub = lane & 15;
    int mynode = blockIdx.x * 64 + wave * 16 + sub;
    int arow = (mynode < n_nodes) ? mynode : (n_nodes - 1);
    const unsigned short* ap = X + (size_t)arow * astride + quad * 8;

    f32x4 acc[NCT];
#pragma unroll
    for (int ct = 0; ct < NCT; ++ct) acc[ct] = (f32x4){0,0,0,0};

    short8 av = *(const short8*)ap;
#pragma unroll
    for (int kt = 0; kt < KT; ++kt) {
        short8 av_next = av;
        if (kt < KT - 1) av_next = *(const short8*)(ap + (kt + 1) * 32);
        int chunk = kt * 4 + quad;
#pragma unroll
        for (int ct = 0; ct < NCT; ++ct) {
            int ncol = ct * 16 + sub;
            union { u32x4 u; short8 s; } cv;
            cv.u = ldsW[ncol * CHK + (chunk ^ (ncol & 7))];
            acc[ct] = __builtin_amdgcn_mfma_f32_16x16x32_bf16(cv.s, av, acc[ct], 0, 0, 0);
        }
        av = av_next;
    }

    float ss = 0.0f;
#pragma unroll
    for (int ct = 0; ct < NCT; ++ct) {
        f32x4 b4 = *(const f32x4*)(bias + ct * 16 + quad * 4);
#pragma unroll
        for (int r = 0; r < 4; ++r) {
            float v = acc[ct][r] + b4[r];
            if (ACTNORM) { v = fmaxf(v, 0.0f); ss += v * v; }
            acc[ct][r] = v;
        }
    }
    float scale = 1.0f;
    if (ACTNORM) {
        ss += __shfl_xor(ss, 16, 64);
        ss += __shfl_xor(ss, 32, 64);
        scale = 1.0f / fmaxf(sqrtf(ss), 1e-12f);
    }
    if (mynode < n_nodes) {
#pragma unroll
        for (int ct = 0; ct < NCT; ++ct) {
            int c0 = ct * 16 + quad * 4;
            u16x4 o = { f2bf(acc[ct][0] * scale), f2bf(acc[ct][1] * scale),
                        f2bf(acc[ct][2] * scale), f2bf(acc[ct][3] * scale) };
            if (DUAL) {
                if (c0 < 40) *(u16x4*)(Zbuf + (size_t)mynode * 40 + c0) = o;
                else         *(u16x4*)(Ybuf + (size_t)mynode * 40 + (c0 - 40)) = o;
            } else {
                *(u16x4*)(out + (size_t)mynode * out_stride + c0) = o;
            }
        }
    }
}

// ---------------------------------------------------------------------------
// Layer-2 finish: out[n] = mean_{nb}(Y2[nb]) + Z2[n]. One wave per node,
// 8 lanes per 80B Y2 row (stride 40; lanes 5..7 read in-region data that is
// discarded by the sub<5 write guard and never crosses the shfl_xor groups).
__global__ void combine_kernel(const unsigned short* __restrict__ Y2,
                               const unsigned short* __restrict__ Z2,
                               const int* __restrict__ csr,
                               const int* __restrict__ row_start,
                               const int* __restrict__ deg,
                               void* __restrict__ out,
                               const int* __restrict__ gflag) {
    int node = blockIdx.x * 4 + (threadIdx.x >> 6);
    if (node >= N_NODES_C) return;
    int lane = threadIdx.x & 63;
    int g = lane >> 3, sub = lane & 7;
    int start = row_start[node], d = deg[node];
    const int* cp = csr + start;
    float a[8] = {0,0,0,0,0,0,0,0};
    int rd = (sub < 5) ? sub : 4;          // keep OOB-safe within allocated rows
    int nfull = d >> 3, rem = d & 7;
    int i = 0;
    for (; i + 2 <= nfull; i += 2) {
        int nb0 = cp[i * 8 + g];
        int nb1 = cp[i * 8 + 8 + g];
        u32x4 r0 = *(const u32x4*)(Y2 + (size_t)nb0 * 40 + rd * 8);
        u32x4 r1 = *(const u32x4*)(Y2 + (size_t)nb1 * 40 + rd * 8);
        acc8(a, r0); acc8(a, r1);
    }
    if (i < nfull) {
        int nb = cp[i * 8 + g];
        u32x4 r = *(const u32x4*)(Y2 + (size_t)nb * 40 + rd * 8);
        acc8(a, r);
    }
    if (g < rem) {
        int nb = cp[nfull * 8 + g];
        u32x4 r = *(const u32x4*)(Y2 + (size_t)nb * 40 + rd * 8);
        acc8(a, r);
    }
#pragma unroll
    for (int j = 0; j < 8; ++j) {
        a[j] += __shfl_xor(a[j], 8, 64);
        a[j] += __shfl_xor(a[j], 16, 64);
        a[j] += __shfl_xor(a[j], 32, 64);
    }
    if (g == 0 && sub < 5) {
        float inv = (d > 0) ? 1.0f / (float)d : 0.0f;
        u32x4 z = *(const u32x4*)(Z2 + (size_t)node * 40 + sub * 8);
        float v[8];
        v[0] = a[0] * inv + bf_lo(z.x); v[1] = a[1] * inv + bf_hi(z.x);
        v[2] = a[2] * inv + bf_lo(z.y); v[3] = a[3] * inv + bf_hi(z.y);
        v[4] = a[4] * inv + bf_lo(z.z); v[5] = a[5] * inv + bf_hi(z.z);
        v[6] = a[6] * inv + bf_lo(z.w); v[7] = a[7] * inv + bf_hi(z.w);
        if (*gflag) {
            u32x4 o;
            o.x = (unsigned)f2bf(v[0]) | ((unsigned)f2bf(v[1]) << 16);
            o.y = (unsigned)f2bf(v[2]) | ((unsigned)f2bf(v[3]) << 16);
            o.z = (unsigned)f2bf(v[4]) | ((unsigned)f2bf(v[5]) << 16);
            o.w = (unsigned)f2bf(v[6]) | ((unsigned)f2bf(v[7]) << 16);
            *(u32x4*)((unsigned short*)out + (size_t)node * 40 + sub * 8) = o;
        } else {
            float* op = (float*)out + (size_t)node * 40 + sub * 8;
            f32x4 o0 = { v[0], v[1], v[2], v[3] };
            f32x4 o1 = { v[4], v[5], v[6], v[7] };
            *(f32x4*)op = o0;
            *(f32x4*)(op + 4) = o1;
        }
    }
}

// ---------------------------------------------------------------------------
extern "C" void kernel_launch(void* const* d_in, const int* in_sizes, int n_in,
                              void* d_out, int out_size, void* d_ws, size_t ws_size,
                              hipStream_t stream) {
    const void* feats = d_in[0];
    const int*  src   = (const int*)d_in[1];
    const int*  dst   = (const int*)d_in[2];

    char* ws = (char*)d_ws;
    unsigned short* H1   = (unsigned short*)ws;                        // 25,600,000 (stride 128)
    unsigned short* H2   = (unsigned short*)(ws + 25600000);           // 25,600,000 (stride 128)
    unsigned short* Wt   = (unsigned short*)(ws + 102400000);          //   ~283,000
    float*          bcat = (float*)(ws + 102912000);                   //     1,344
    unsigned short* Y2   = (unsigned short*)(ws + 102916096);          //  8,000,000 (stride 40)
    unsigned short* Z2   = (unsigned short*)(ws + 115716096);          //  8,000,000 (stride 40)
    unsigned*       pairs= (unsigned*)(ws + 102916096);                // alias Y2 (pre-GEMM only), 7.2 MB
    int*  csr       = (int*)(ws + 128516096);                          //  6,400,000
    int*  row_start = (int*)(ws + 134916096);                          //    400,000
    int*  deg       = (int*)(ws + 135316096);                          //    400,000
    int*  boff      = (int*)(ws + 135718144);                          // (N_BUCK+1)*4
    int*  bcur      = (int*)(ws + 135720192);                          // N_BUCK*4
    int*  gflag     = (int*)(ws + 135722240);

    // ---- dtype probe + bucket cursor init (no memsets needed) ----
    detect_init<<<1, 64, 0, stream>>>(feats, gflag, bcur);

    // ---- bucketed CSR build ----
    partition2<<<PART_NB, 256, 0, stream>>>(src, dst, bcur, pairs);
    mkboff_kernel<<<1, 64, 0, stream>>>(bcur, boff);
    bucket_fill<<<N_BUCK, 256, 0, stream>>>(pairs, boff, csr, row_start, deg);

    // ---- weights ----
    prep_weights<<<336, 256, 0, stream>>>(
        d_in[3], d_in[4], d_in[5], d_in[6],
        d_in[7], d_in[8], d_in[9], d_in[10],
        d_in[11], d_in[12], d_in[13], d_in[14], Wt, bcat, gflag);

    const int fblk = (N_NODES_C + FB_NODES - 1) / FB_NODES;   // 1563
    const int cblk = (N_NODES_C + 3) / 4;
    const int mblk = (N_NODES_C + 63) / 64;

    // layer 0: feats -> h1 (gather+GEMM fused)
    fused_layer<<<fblk, 256, 0, stream>>>(
        feats, 128, 2, csr, row_start, deg,
        (const u32x4*)Wt, bcat, H1, N_NODES_C, gflag);

    // layer 1: h1 -> h2 (gather+GEMM fused)
    fused_layer<<<fblk, 256, 0, stream>>>(
        H1, 128, 1, csr, row_start, deg,
        (const u32x4*)(Wt + 128 * 256), bcat + 128, H2, N_NODES_C, gflag);

    // layer 2 (transform-then-aggregate): h2 -> Y2 = h2@Wn2, Z2 = h2@Ws2 + b
    mfma_gemm<5, 4, 16, false, true><<<mblk, 256, 0, stream>>>(
        H2, 128, (const u32x4*)(Wt + 65536), bcat + 256, nullptr, 0, Y2, Z2, N_NODES_C);

    // out = mean(Y2[nbrs]) + Z2
    combine_kernel<<<cblk, 256, 0, stream>>>(Y2, Z2, csr, row_start, deg, d_out, gflag);
}

// Round 5
// 469.943 us; speedup vs baseline: 1.0721x; 1.0721x over previous
//
#include <hip/hip_runtime.h>
#include <hip/hip_bf16.h>

#define N_NODES_C 100000
#define N_EDGES_C 1600000
#define N_BUCK ((N_NODES_C + 255) / 256)   // 391
#define BCAP 4608                          // per-bucket capacity, mean 4092 + 8 sigma
#define PART_NB 160
#define PART_CHUNK ((N_EDGES_C + PART_NB - 1) / PART_NB)  // 10000

typedef __attribute__((ext_vector_type(8))) short          short8;   // 8 bf16
typedef __attribute__((ext_vector_type(4))) float          f32x4;
typedef __attribute__((ext_vector_type(4))) unsigned int   u32x4;
typedef __attribute__((ext_vector_type(4))) unsigned short u16x4;

// ---------------------------------------------------------------------------
__device__ inline float load1v(const void* p, size_t i, int bf) {
    return bf ? __bfloat162float(((const __hip_bfloat16*)p)[i])
              : ((const float*)p)[i];
}
__device__ inline unsigned short f2bf(float f) {
    __hip_bfloat16 h = __float2bfloat16(f);
    return *reinterpret_cast<unsigned short*>(&h);
}
__device__ inline float bf_lo(unsigned u) { return __uint_as_float(u << 16); }
__device__ inline float bf_hi(unsigned u) { return __uint_as_float(u & 0xffff0000u); }
__device__ inline void acc8(float* a, u32x4 r) {
    a[0] += bf_lo(r.x); a[1] += bf_hi(r.x);
    a[2] += bf_lo(r.y); a[3] += bf_hi(r.y);
    a[4] += bf_lo(r.z); a[5] += bf_hi(r.z);
    a[6] += bf_lo(r.w); a[7] += bf_hi(r.w);
}

// ---------------------------------------------------------------------------
// Dtype probe (gflag=1 iff float tensors are bf16) + bucket cursor init.
__global__ void detect_init(const void* __restrict__ feats, int* __restrict__ gflag,
                            int* __restrict__ bcur) {
    const unsigned short* u = (const unsigned short*)feats;
    int bad = 0;
    for (int i = threadIdx.x; i < 2048; i += 64) {
        unsigned e = (u[i] >> 7) & 0xFF;
        if (e >= 0xC0) bad++;
    }
#pragma unroll
    for (int off = 32; off > 0; off >>= 1) bad += __shfl_down(bad, off, 64);
    if (threadIdx.x == 0) *gflag = (bad == 0) ? 1 : 0;
    for (int b = threadIdx.x; b < N_BUCK; b += 64) bcur[b] = b * BCAP;
}

// ---------------------------------------------------------------------------
// Privatized two-pass partition into FIXED-CAP bucket slots.
__global__ __launch_bounds__(256) void partition2(
        const int* __restrict__ src, const int* __restrict__ dst,
        int* __restrict__ bcur, unsigned* __restrict__ pairs) {
    __shared__ int cnt[N_BUCK];
    __shared__ int lbase[N_BUCK];
    int tid = threadIdx.x;
    int e0 = blockIdx.x * PART_CHUNK;
    int e1 = min(e0 + PART_CHUNK, N_EDGES_C);
    for (int i = tid; i < N_BUCK; i += 256) cnt[i] = 0;
    __syncthreads();
    for (int e = e0 + tid; e < e1; e += 256)
        atomicAdd(&cnt[dst[e] >> 8], 1);
    __syncthreads();
    for (int i = tid; i < N_BUCK; i += 256) {
        int c = cnt[i];
        lbase[i] = c ? atomicAdd(&bcur[i], c) : 0;
        cnt[i] = 0;                       // reuse as local cursor
    }
    __syncthreads();
    for (int e = e0 + tid; e < e1; e += 256) {
        int s = src[e], d = dst[e];
        int bk = d >> 8;
        int pos = lbase[bk] + atomicAdd(&cnt[bk], 1);
        pairs[pos] = ((unsigned)(d & 255) << 17) | (unsigned)s;
    }
}

// Compact csr offsets from bucket fill levels (LDS-staged)
__global__ void mkboff_kernel(const int* __restrict__ bcur, int* __restrict__ boff) {
    __shared__ int c[N_BUCK];
    int tid = threadIdx.x;
    for (int i = tid; i < N_BUCK; i += 64) c[i] = bcur[i] - i * BCAP;
    __syncthreads();
    if (tid == 0) {
        int run = 0;
        for (int b = 0; b < N_BUCK; ++b) { int t = c[b]; c[b] = run; run += t; }
        boff[N_BUCK] = run;
    }
    __syncthreads();
    for (int i = tid; i < N_BUCK; i += 64) boff[i] = c[i];
}

// One block per bucket: per-node count + LDS scan -> row_start/deg, then emit
// csr (compact layout at boff) from the padded pairs window at b*BCAP.
__global__ __launch_bounds__(256) void bucket_fill(
        const unsigned* __restrict__ pairs, const int* __restrict__ boff,
        int* __restrict__ csr, int* __restrict__ row_start, int* __restrict__ deg) {
    __shared__ int cnt[256], sd[256], lcur[256];
    int b = blockIdx.x, tid = threadIdx.x;
    int pbase = b * BCAP;
    int base = boff[b], count = boff[b + 1] - base;
    cnt[tid] = 0;
    __syncthreads();
    for (int i = tid; i < count; i += 256)
        atomicAdd(&cnt[pairs[pbase + i] >> 17], 1);
    __syncthreads();
    sd[tid] = cnt[tid];
    __syncthreads();
    for (int st = 1; st < 256; st <<= 1) {
        int t = (tid >= st) ? sd[tid - st] : 0;
        __syncthreads();
        sd[tid] += t;
        __syncthreads();
    }
    int excl = sd[tid] - cnt[tid];
    int node = b * 256 + tid;
    if (node < N_NODES_C) { row_start[node] = base + excl; deg[node] = cnt[tid]; }
    lcur[tid] = excl;
    __syncthreads();
    for (int i = tid; i < count; i += 256) {
        unsigned p = pairs[pbase + i];
        int pos = base + atomicAdd(&lcur[p >> 17], 1);
        csr[pos] = (int)(p & 0x1FFFFu);
    }
}

// ---------------------------------------------------------------------------
// Weight prep. Wt rows 0..127: L0 (K=256); 128..255: L1 (K=256);
// L2 compact at Wt+65536: 80 rows x K=128 (cols 0..39 = Ws2, 40..79 = Wn2).
__global__ void prep_weights(const void* Ws0, const void* bs0, const void* Wn0, const void* bn0,
                             const void* Ws1, const void* bs1, const void* Wn1, const void* bn1,
                             const void* Ws2, const void* bs2, const void* Wn2, const void* bn2,
                             unsigned short* __restrict__ Wt, float* __restrict__ bcat,
                             const int* __restrict__ gflag) {
    int gb = *gflag;
    int n = blockIdx.x;        // 0..335
    int k = threadIdx.x;       // 0..255
    if (n < 128) {
        float v = (k < 128) ? load1v(Ws0, (size_t)k * 128 + n, gb)
                            : load1v(Wn0, (size_t)(k - 128) * 128 + n, gb);
        Wt[(size_t)n * 256 + k] = f2bf(v);
        if (k == 0) bcat[n] = load1v(bs0, n, gb) + load1v(bn0, n, gb);
    } else if (n < 256) {
        int c = n - 128;
        float v = (k < 128) ? load1v(Ws1, (size_t)k * 128 + c, gb)
                            : load1v(Wn1, (size_t)(k - 128) * 128 + c, gb);
        Wt[(size_t)n * 256 + k] = f2bf(v);
        if (k == 0) bcat[n] = load1v(bs1, c, gb) + load1v(bn1, c, gb);
    } else {
        int c = n - 256;       // 0..79
        if (k < 128) {
            float v = (c < 40) ? load1v(Ws2, (size_t)k * 40 + c, gb)
                               : load1v(Wn2, (size_t)k * 40 + (c - 40), gb);
            Wt[65536 + (size_t)c * 128 + k] = f2bf(v);
        }
        if (k == 0) bcat[n] = (c < 40) ? load1v(bs2, c, gb) + load1v(bn2, c, gb) : 0.0f;
    }
}

// ---------------------------------------------------------------------------
// Gather-mean (round-2 proven structure): one node per 16-lane GROUP
// (4 nodes/wave). Writes mean into compact Xmean (stride 128 bf16).
// Self copy is ONLY materialized in the f32-input fallback (Sout, stride 128);
// in the bf16 case the GEMM reads self directly from the source tensor.
__global__ __launch_bounds__(256) void gather_kernel(
        const void* __restrict__ hsrc, int src_stride,
        int src_mode, int copy_self,
        const int* __restrict__ csr,
        const int* __restrict__ row_start,
        const int* __restrict__ deg,
        unsigned short* __restrict__ Xmean,
        unsigned short* __restrict__ Sout,
        const int* __restrict__ gflag) {
    int wave = threadIdx.x >> 6, lane = threadIdx.x & 63;
    int g = lane >> 4, sub = lane & 15;
    int srcLane = lane & 48;                       // g*16
    int node = blockIdx.x * 16 + wave * 4 + g;
    bool valid = node < N_NODES_C;
    int vnode = valid ? node : (N_NODES_C - 1);
    int start = row_start[vnode];
    int d = valid ? deg[vnode] : 0;
    const int* cp = csr + start;
    float inv = (d > 0) ? 1.0f / (float)d : 0.0f;
    int bf = (src_mode == 2) ? *gflag : src_mode;

    if (bf) {
        const unsigned short* hb = (const unsigned short*)hsrc;
        float a[8] = {0, 0, 0, 0, 0, 0, 0, 0};
        for (int base = 0; base < d; base += 16) {
            int n16 = min(d - base, 16);
            int idxr = cp[base + ((sub < n16) ? sub : 0)];
            int i = 0;
            for (; i + 8 <= n16; i += 8) {
                int nb0 = __shfl(idxr, srcLane + i + 0, 64);
                int nb1 = __shfl(idxr, srcLane + i + 1, 64);
                int nb2 = __shfl(idxr, srcLane + i + 2, 64);
                int nb3 = __shfl(idxr, srcLane + i + 3, 64);
                int nb4 = __shfl(idxr, srcLane + i + 4, 64);
                int nb5 = __shfl(idxr, srcLane + i + 5, 64);
                int nb6 = __shfl(idxr, srcLane + i + 6, 64);
                int nb7 = __shfl(idxr, srcLane + i + 7, 64);
                u32x4 r0 = *(const u32x4*)(hb + (size_t)nb0 * src_stride + sub * 8);
                u32x4 r1 = *(const u32x4*)(hb + (size_t)nb1 * src_stride + sub * 8);
                u32x4 r2 = *(const u32x4*)(hb + (size_t)nb2 * src_stride + sub * 8);
                u32x4 r3 = *(const u32x4*)(hb + (size_t)nb3 * src_stride + sub * 8);
                u32x4 r4 = *(const u32x4*)(hb + (size_t)nb4 * src_stride + sub * 8);
                u32x4 r5 = *(const u32x4*)(hb + (size_t)nb5 * src_stride + sub * 8);
                u32x4 r6 = *(const u32x4*)(hb + (size_t)nb6 * src_stride + sub * 8);
                u32x4 r7 = *(const u32x4*)(hb + (size_t)nb7 * src_stride + sub * 8);
                acc8(a, r0); acc8(a, r1); acc8(a, r2); acc8(a, r3);
                acc8(a, r4); acc8(a, r5); acc8(a, r6); acc8(a, r7);
            }
            for (; i + 4 <= n16; i += 4) {
                int nb0 = __shfl(idxr, srcLane + i + 0, 64);
                int nb1 = __shfl(idxr, srcLane + i + 1, 64);
                int nb2 = __shfl(idxr, srcLane + i + 2, 64);
                int nb3 = __shfl(idxr, srcLane + i + 3, 64);
                u32x4 r0 = *(const u32x4*)(hb + (size_t)nb0 * src_stride + sub * 8);
                u32x4 r1 = *(const u32x4*)(hb + (size_t)nb1 * src_stride + sub * 8);
                u32x4 r2 = *(const u32x4*)(hb + (size_t)nb2 * src_stride + sub * 8);
                u32x4 r3 = *(const u32x4*)(hb + (size_t)nb3 * src_stride + sub * 8);
                acc8(a, r0); acc8(a, r1); acc8(a, r2); acc8(a, r3);
            }
            for (; i < n16; ++i) {
                int nb = __shfl(idxr, srcLane + i, 64);
                u32x4 r = *(const u32x4*)(hb + (size_t)nb * src_stride + sub * 8);
                acc8(a, r);
            }
        }
        if (valid) {
            u32x4 o;
            o.x = (unsigned)f2bf(a[0] * inv) | ((unsigned)f2bf(a[1] * inv) << 16);
            o.y = (unsigned)f2bf(a[2] * inv) | ((unsigned)f2bf(a[3] * inv) << 16);
            o.z = (unsigned)f2bf(a[4] * inv) | ((unsigned)f2bf(a[5] * inv) << 16);
            o.w = (unsigned)f2bf(a[6] * inv) | ((unsigned)f2bf(a[7] * inv) << 16);
            *(u32x4*)(Xmean + (size_t)node * 128 + sub * 8) = o;
            // bf16 self: GEMM reads hsrc directly; no copy.
        }
    } else {
        const float* hf = (const float*)hsrc;
        float a[8] = {0, 0, 0, 0, 0, 0, 0, 0};
        for (int base = 0; base < d; base += 16) {
            int n16 = min(d - base, 16);
            int idxr = cp[base + ((sub < n16) ? sub : 0)];
            int i = 0;
            for (; i + 4 <= n16; i += 4) {
                int nb0 = __shfl(idxr, srcLane + i + 0, 64);
                int nb1 = __shfl(idxr, srcLane + i + 1, 64);
                int nb2 = __shfl(idxr, srcLane + i + 2, 64);
                int nb3 = __shfl(idxr, srcLane + i + 3, 64);
                const float* p0 = hf + (size_t)nb0 * src_stride + sub * 4;
                const float* p1 = hf + (size_t)nb1 * src_stride + sub * 4;
                const float* p2 = hf + (size_t)nb2 * src_stride + sub * 4;
                const float* p3 = hf + (size_t)nb3 * src_stride + sub * 4;
                f32x4 a0 = *(const f32x4*)p0, b0 = *(const f32x4*)(p0 + 64);
                f32x4 a1 = *(const f32x4*)p1, b1 = *(const f32x4*)(p1 + 64);
                f32x4 a2 = *(const f32x4*)p2, b2 = *(const f32x4*)(p2 + 64);
                f32x4 a3 = *(const f32x4*)p3, b3 = *(const f32x4*)(p3 + 64);
#pragma unroll
                for (int k = 0; k < 4; ++k) {
                    a[k] += a0[k] + a1[k] + a2[k] + a3[k];
                    a[4 + k] += b0[k] + b1[k] + b2[k] + b3[k];
                }
            }
            for (; i < n16; ++i) {
                int nb = __shfl(idxr, srcLane + i, 64);
                const float* p0 = hf + (size_t)nb * src_stride + sub * 4;
                f32x4 a0 = *(const f32x4*)p0, b0 = *(const f32x4*)(p0 + 64);
#pragma unroll
                for (int k = 0; k < 4; ++k) { a[k] += a0[k]; a[4 + k] += b0[k]; }
            }
        }
        if (valid) {
            u16x4 oa = { f2bf(a[0] * inv), f2bf(a[1] * inv),
                         f2bf(a[2] * inv), f2bf(a[3] * inv) };
            u16x4 ob = { f2bf(a[4] * inv), f2bf(a[5] * inv),
                         f2bf(a[6] * inv), f2bf(a[7] * inv) };
            *(u16x4*)(Xmean + (size_t)node * 128 + sub * 4) = oa;
            *(u16x4*)(Xmean + (size_t)node * 128 + 64 + sub * 4) = ob;
            if (copy_self) {
                const float* sp = hf + (size_t)node * src_stride + sub * 4;
                f32x4 ra = *(const f32x4*)sp;
                f32x4 rb = *(const f32x4*)(sp + 64);
                u16x4 sa = { f2bf(ra.x), f2bf(ra.y), f2bf(ra.z), f2bf(ra.w) };
                u16x4 sb = { f2bf(rb.x), f2bf(rb.y), f2bf(rb.z), f2bf(rb.w) };
                *(u16x4*)(Sout + (size_t)node * 128 + sub * 4) = sa;
                *(u16x4*)(Sout + (size_t)node * 128 + 64 + sub * 4) = sb;
            }
        }
    }
}

// ---------------------------------------------------------------------------
// Split-A MFMA GEMM for layers 0/1: A = [self | mean], self from AselfA
// (or AselfB when *gflag==0 and use_flag), mean from Amean; both stride 128.
// K=256 (kt 0..3 = self cols, kt 4..7 = mean cols), N=128, relu+l2norm.
__global__ __launch_bounds__(256) void mfma_gemm_split(
        const unsigned short* __restrict__ AselfA,
        const unsigned short* __restrict__ AselfB,
        const unsigned short* __restrict__ Amean,
        const u32x4* __restrict__ Wg,           // [128][32] 16B chunks
        const float* __restrict__ bias,         // [128]
        unsigned short* __restrict__ hout,      // stride 128 bf16
        int n_nodes, const int* __restrict__ gflag, int use_flag) {
    __shared__ u32x4 ldsW[128 * 32];            // 64 KB
    int tid = threadIdx.x;
    for (int c = tid; c < 128 * 32; c += 256) {
        int nrow = c >> 5, ch = c & 31;
        ldsW[(nrow << 5) + (ch ^ (nrow & 7))] = Wg[c];
    }
    __syncthreads();

    const unsigned short* Aself = AselfA;
    if (use_flag && *gflag == 0) Aself = AselfB;

    int wave = tid >> 6, lane = tid & 63;
    int quad = lane >> 4, sub = lane & 15;
    int mynode = blockIdx.x * 64 + wave * 16 + sub;
    int arow = (mynode < n_nodes) ? mynode : (n_nodes - 1);
    const unsigned short* apS = Aself + (size_t)arow * 128 + quad * 8;
    const unsigned short* apM = Amean + (size_t)arow * 128 + quad * 8;

    f32x4 acc[8];
#pragma unroll
    for (int ct = 0; ct < 8; ++ct) acc[ct] = (f32x4){0, 0, 0, 0};

    short8 av = *(const short8*)apS;
#pragma unroll
    for (int kt = 0; kt < 8; ++kt) {
        short8 av_next = av;
        if (kt < 7) {
            int kn = kt + 1;
            av_next = (kn < 4) ? *(const short8*)(apS + kn * 32)
                               : *(const short8*)(apM + (kn - 4) * 32);
        }
        int chunk = kt * 4 + quad;
#pragma unroll
        for (int ct = 0; ct < 8; ++ct) {
            int ncol = ct * 16 + sub;
            union { u32x4 u; short8 s; } cv;
            cv.u = ldsW[(ncol << 5) + (chunk ^ (ncol & 7))];
            acc[ct] = __builtin_amdgcn_mfma_f32_16x16x32_bf16(cv.s, av, acc[ct], 0, 0, 0);
        }
        av = av_next;
    }

    float ss = 0.0f;
#pragma unroll
    for (int ct = 0; ct < 8; ++ct) {
        f32x4 b4 = *(const f32x4*)(bias + ct * 16 + quad * 4);
#pragma unroll
        for (int r = 0; r < 4; ++r) {
            float v = acc[ct][r] + b4[r];
            v = fmaxf(v, 0.0f); ss += v * v;
            acc[ct][r] = v;
        }
    }
    ss += __shfl_xor(ss, 16, 64);
    ss += __shfl_xor(ss, 32, 64);
    float scale = 1.0f / fmaxf(sqrtf(ss), 1e-12f);
    if (mynode < n_nodes) {
#pragma unroll
        for (int ct = 0; ct < 8; ++ct) {
            int c0 = ct * 16 + quad * 4;
            u16x4 o = { f2bf(acc[ct][0] * scale), f2bf(acc[ct][1] * scale),
                        f2bf(acc[ct][2] * scale), f2bf(acc[ct][3] * scale) };
            *(u16x4*)(hout + (size_t)mynode * 128 + c0) = o;
        }
    }
}

// ---------------------------------------------------------------------------
// MFMA GEMM (layer 2). DUAL: cols 0..39 -> Zbuf (stride 40),
// cols 40..79 -> Ybuf (stride 40).
template <int NCT, int KT, int CHK, bool ACTNORM, bool DUAL>
__global__ __launch_bounds__(256) void mfma_gemm(
        const unsigned short* __restrict__ X, int astride,
        const u32x4* __restrict__ Wg,           // [NCT*16][CHK] 16B chunks
        const float* __restrict__ bias,         // [NCT*16]
        unsigned short* __restrict__ out, int out_stride,
        unsigned short* __restrict__ Ybuf, unsigned short* __restrict__ Zbuf,
        int n_nodes) {
    __shared__ u32x4 ldsW[NCT * 16 * CHK];
    int tid = threadIdx.x;
    for (int c = tid; c < NCT * 16 * CHK; c += 256) {
        int nrow = c / CHK, ch = c % CHK;
        ldsW[nrow * CHK + (ch ^ (nrow & 7))] = Wg[c];
    }
    __syncthreads();

    int wave = tid >> 6, lane = tid & 63;
    int quad = lane >> 4, sub = lane & 15;
    int mynode = blockIdx.x * 64 + wave * 16 + sub;
    int arow = (mynode < n_nodes) ? mynode : (n_nodes - 1);
    const unsigned short* ap = X + (size_t)arow * astride + quad * 8;

    f32x4 acc[NCT];
#pragma unroll
    for (int ct = 0; ct < NCT; ++ct) acc[ct] = (f32x4){0,0,0,0};

    short8 av = *(const short8*)ap;
#pragma unroll
    for (int kt = 0; kt < KT; ++kt) {
        short8 av_next = av;
        if (kt < KT - 1) av_next = *(const short8*)(ap + (kt + 1) * 32);
        int chunk = kt * 4 + quad;
#pragma unroll
        for (int ct = 0; ct < NCT; ++ct) {
            int ncol = ct * 16 + sub;
            union { u32x4 u; short8 s; } cv;
            cv.u = ldsW[ncol * CHK + (chunk ^ (ncol & 7))];
            acc[ct] = __builtin_amdgcn_mfma_f32_16x16x32_bf16(cv.s, av, acc[ct], 0, 0, 0);
        }
        av = av_next;
    }

    float ss = 0.0f;
#pragma unroll
    for (int ct = 0; ct < NCT; ++ct) {
        f32x4 b4 = *(const f32x4*)(bias + ct * 16 + quad * 4);
#pragma unroll
        for (int r = 0; r < 4; ++r) {
            float v = acc[ct][r] + b4[r];
            if (ACTNORM) { v = fmaxf(v, 0.0f); ss += v * v; }
            acc[ct][r] = v;
        }
    }
    float scale = 1.0f;
    if (ACTNORM) {
        ss += __shfl_xor(ss, 16, 64);
        ss += __shfl_xor(ss, 32, 64);
        scale = 1.0f / fmaxf(sqrtf(ss), 1e-12f);
    }
    if (mynode < n_nodes) {
#pragma unroll
        for (int ct = 0; ct < NCT; ++ct) {
            int c0 = ct * 16 + quad * 4;
            u16x4 o = { f2bf(acc[ct][0] * scale), f2bf(acc[ct][1] * scale),
                        f2bf(acc[ct][2] * scale), f2bf(acc[ct][3] * scale) };
            if (DUAL) {
                if (c0 < 40) *(u16x4*)(Zbuf + (size_t)mynode * 40 + c0) = o;
                else         *(u16x4*)(Ybuf + (size_t)mynode * 40 + (c0 - 40)) = o;
            } else {
                *(u16x4*)(out + (size_t)mynode * out_stride + c0) = o;
            }
        }
    }
}

// ---------------------------------------------------------------------------
// Layer-2 finish: out[n] = mean_{nb}(Y2[nb]) + Z2[n]. One wave per node,
// 8 lanes per 80B Y2 row (stride 40; lanes 5..7 read in-region data that is
// discarded by the sub<5 write guard and never crosses the shfl_xor groups).
__global__ void combine_kernel(const unsigned short* __restrict__ Y2,
                               const unsigned short* __restrict__ Z2,
                               const int* __restrict__ csr,
                               const int* __restrict__ row_start,
                               const int* __restrict__ deg,
                               void* __restrict__ out,
                               const int* __restrict__ gflag) {
    int node = blockIdx.x * 4 + (threadIdx.x >> 6);
    if (node >= N_NODES_C) return;
    int lane = threadIdx.x & 63;
    int g = lane >> 3, sub = lane & 7;
    int start = row_start[node], d = deg[node];
    const int* cp = csr + start;
    float a[8] = {0,0,0,0,0,0,0,0};
    int rd = (sub < 5) ? sub : 4;          // keep OOB-safe within allocated rows
    int nfull = d >> 3, rem = d & 7;
    int i = 0;
    for (; i + 2 <= nfull; i += 2) {
        int nb0 = cp[i * 8 + g];
        int nb1 = cp[i * 8 + 8 + g];
        u32x4 r0 = *(const u32x4*)(Y2 + (size_t)nb0 * 40 + rd * 8);
        u32x4 r1 = *(const u32x4*)(Y2 + (size_t)nb1 * 40 + rd * 8);
        acc8(a, r0); acc8(a, r1);
    }
    if (i < nfull) {
        int nb = cp[i * 8 + g];
        u32x4 r = *(const u32x4*)(Y2 + (size_t)nb * 40 + rd * 8);
        acc8(a, r);
    }
    if (g < rem) {
        int nb = cp[nfull * 8 + g];
        u32x4 r = *(const u32x4*)(Y2 + (size_t)nb * 40 + rd * 8);
        acc8(a, r);
    }
#pragma unroll
    for (int j = 0; j < 8; ++j) {
        a[j] += __shfl_xor(a[j], 8, 64);
        a[j] += __shfl_xor(a[j], 16, 64);
        a[j] += __shfl_xor(a[j], 32, 64);
    }
    if (g == 0 && sub < 5) {
        float inv = (d > 0) ? 1.0f / (float)d : 0.0f;
        u32x4 z = *(const u32x4*)(Z2 + (size_t)node * 40 + sub * 8);
        float v[8];
        v[0] = a[0] * inv + bf_lo(z.x); v[1] = a[1] * inv + bf_hi(z.x);
        v[2] = a[2] * inv + bf_lo(z.y); v[3] = a[3] * inv + bf_hi(z.y);
        v[4] = a[4] * inv + bf_lo(z.z); v[5] = a[5] * inv + bf_hi(z.z);
        v[6] = a[6] * inv + bf_lo(z.w); v[7] = a[7] * inv + bf_hi(z.w);
        if (*gflag) {
            u32x4 o;
            o.x = (unsigned)f2bf(v[0]) | ((unsigned)f2bf(v[1]) << 16);
            o.y = (unsigned)f2bf(v[2]) | ((unsigned)f2bf(v[3]) << 16);
            o.z = (unsigned)f2bf(v[4]) | ((unsigned)f2bf(v[5]) << 16);
            o.w = (unsigned)f2bf(v[6]) | ((unsigned)f2bf(v[7]) << 16);
            *(u32x4*)((unsigned short*)out + (size_t)node * 40 + sub * 8) = o;
        } else {
            float* op = (float*)out + (size_t)node * 40 + sub * 8;
            f32x4 o0 = { v[0], v[1], v[2], v[3] };
            f32x4 o1 = { v[4], v[5], v[6], v[7] };
            *(f32x4*)op = o0;
            *(f32x4*)(op + 4) = o1;
        }
    }
}

// ---------------------------------------------------------------------------
extern "C" void kernel_launch(void* const* d_in, const int* in_sizes, int n_in,
                              void* d_out, int out_size, void* d_ws, size_t ws_size,
                              hipStream_t stream) {
    const void* feats = d_in[0];
    const int*  src   = (const int*)d_in[1];
    const int*  dst   = (const int*)d_in[2];

    char* ws = (char*)d_ws;
    unsigned short* MEAN = (unsigned short*)ws;                        // 25,600,000 (stride 128)
    unsigned short* H1   = (unsigned short*)(ws + 25600000);           // 25,600,000 (stride 128)
    unsigned short* H2   = (unsigned short*)(ws + 51200000);           // 25,600,000 (stride 128)
    unsigned short* S0   = (unsigned short*)(ws + 76800000);           // 25,600,000 (f32 fallback self)
    unsigned short* Wt   = (unsigned short*)(ws + 102400000);          //   ~283,000
    float*          bcat = (float*)(ws + 102912000);                   //     1,344
    unsigned short* Y2   = (unsigned short*)(ws + 102916096);          //  8,000,000 (stride 40)
    unsigned short* Z2   = (unsigned short*)(ws + 115716096);          //  8,000,000 (stride 40)
    unsigned*       pairs= (unsigned*)(ws + 102916096);                // alias Y2 (pre-GEMM only), 7.2 MB
    int*  csr       = (int*)(ws + 128516096);                          //  6,400,000
    int*  row_start = (int*)(ws + 134916096);                          //    400,000
    int*  deg       = (int*)(ws + 135316096);                          //    400,000
    int*  boff      = (int*)(ws + 135718144);                          // (N_BUCK+1)*4
    int*  bcur      = (int*)(ws + 135720192);                          // N_BUCK*4
    int*  gflag     = (int*)(ws + 135722240);

    // ---- dtype probe + bucket cursor init (no memsets needed) ----
    detect_init<<<1, 64, 0, stream>>>(feats, gflag, bcur);

    // ---- bucketed CSR build ----
    partition2<<<PART_NB, 256, 0, stream>>>(src, dst, bcur, pairs);
    mkboff_kernel<<<1, 64, 0, stream>>>(bcur, boff);
    bucket_fill<<<N_BUCK, 256, 0, stream>>>(pairs, boff, csr, row_start, deg);

    // ---- weights ----
    prep_weights<<<336, 256, 0, stream>>>(
        d_in[3], d_in[4], d_in[5], d_in[6],
        d_in[7], d_in[8], d_in[9], d_in[10],
        d_in[11], d_in[12], d_in[13], d_in[14], Wt, bcat, gflag);

    const int gblk = (N_NODES_C + 15) / 16;   // 4 nodes/wave, 16 nodes/block
    const int cblk = (N_NODES_C + 3) / 4;
    const int mblk = (N_NODES_C + 63) / 64;

    // layer 0: feats -> MEAN (+S0 if f32); h1 = actnorm([self|mean] @ W0 + b0)
    gather_kernel<<<gblk, 256, 0, stream>>>(feats, 128, 2, 1, csr, row_start, deg,
                                            MEAN, S0, gflag);
    mfma_gemm_split<<<mblk, 256, 0, stream>>>(
        (const unsigned short*)feats, S0, MEAN,
        (const u32x4*)Wt, bcat, H1, N_NODES_C, gflag, 1);

    // layer 1: h1 -> MEAN; h2 = actnorm([h1|mean] @ W1 + b1)
    gather_kernel<<<gblk, 256, 0, stream>>>(H1, 128, 1, 0, csr, row_start, deg,
                                            MEAN, nullptr, gflag);
    mfma_gemm_split<<<mblk, 256, 0, stream>>>(
        H1, H1, MEAN,
        (const u32x4*)(Wt + 128 * 256), bcat + 128, H2, N_NODES_C, gflag, 0);

    // layer 2 (transform-then-aggregate): h2 -> Y2 = h2@Wn2, Z2 = h2@Ws2 + b
    mfma_gemm<5, 4, 16, false, true><<<mblk, 256, 0, stream>>>(
        H2, 128, (const u32x4*)(Wt + 65536), bcat + 256, nullptr, 0, Y2, Z2, N_NODES_C);

    // out = mean(Y2[nbrs]) + Z2
    combine_kernel<<<cblk, 256, 0, stream>>>(Y2, Z2, csr, row_start, deg, d_out, gflag);
}

// Round 6
// 460.837 us; speedup vs baseline: 1.0933x; 1.0198x over previous
//
#include <hip/hip_runtime.h>
#include <hip/hip_bf16.h>

#define N_NODES_C 100000
#define N_EDGES_C 1600000
#define N_BUCK ((N_NODES_C + 255) / 256)   // 391
#define BCAP 4608                          // per-bucket capacity, mean 4092 + 8 sigma
#define PART_NB 160
#define PART_CHUNK ((N_EDGES_C + PART_NB - 1) / PART_NB)  // 10000

typedef __attribute__((ext_vector_type(8))) short          short8;   // 8 bf16
typedef __attribute__((ext_vector_type(4))) float          f32x4;
typedef __attribute__((ext_vector_type(4))) unsigned int   u32x4;
typedef __attribute__((ext_vector_type(4))) unsigned short u16x4;

// ---------------------------------------------------------------------------
__device__ inline float load1v(const void* p, size_t i, int bf) {
    return bf ? __bfloat162float(((const __hip_bfloat16*)p)[i])
              : ((const float*)p)[i];
}
__device__ inline unsigned short f2bf(float f) {
    __hip_bfloat16 h = __float2bfloat16(f);
    return *reinterpret_cast<unsigned short*>(&h);
}
__device__ inline float bf_lo(unsigned u) { return __uint_as_float(u << 16); }
__device__ inline float bf_hi(unsigned u) { return __uint_as_float(u & 0xffff0000u); }
__device__ inline void acc8(float* a, u32x4 r) {
    a[0] += bf_lo(r.x); a[1] += bf_hi(r.x);
    a[2] += bf_lo(r.y); a[3] += bf_hi(r.y);
    a[4] += bf_lo(r.z); a[5] += bf_hi(r.z);
    a[6] += bf_lo(r.w); a[7] += bf_hi(r.w);
}

// ---------------------------------------------------------------------------
// Dtype probe (gflag=1 iff float tensors are bf16) + bucket cursor init.
__global__ void detect_init(const void* __restrict__ feats, int* __restrict__ gflag,
                            int* __restrict__ bcur) {
    const unsigned short* u = (const unsigned short*)feats;
    int bad = 0;
    for (int i = threadIdx.x; i < 2048; i += 64) {
        unsigned e = (u[i] >> 7) & 0xFF;
        if (e >= 0xC0) bad++;
    }
#pragma unroll
    for (int off = 32; off > 0; off >>= 1) bad += __shfl_down(bad, off, 64);
    if (threadIdx.x == 0) *gflag = (bad == 0) ? 1 : 0;
    for (int b = threadIdx.x; b < N_BUCK; b += 64) bcur[b] = b * BCAP;
}

// ---------------------------------------------------------------------------
// Privatized two-pass partition into FIXED-CAP bucket slots.
__global__ __launch_bounds__(256) void partition2(
        const int* __restrict__ src, const int* __restrict__ dst,
        int* __restrict__ bcur, unsigned* __restrict__ pairs) {
    __shared__ int cnt[N_BUCK];
    __shared__ int lbase[N_BUCK];
    int tid = threadIdx.x;
    int e0 = blockIdx.x * PART_CHUNK;
    int e1 = min(e0 + PART_CHUNK, N_EDGES_C);
    for (int i = tid; i < N_BUCK; i += 256) cnt[i] = 0;
    __syncthreads();
    for (int e = e0 + tid; e < e1; e += 256)
        atomicAdd(&cnt[dst[e] >> 8], 1);
    __syncthreads();
    for (int i = tid; i < N_BUCK; i += 256) {
        int c = cnt[i];
        lbase[i] = c ? atomicAdd(&bcur[i], c) : 0;
        cnt[i] = 0;                       // reuse as local cursor
    }
    __syncthreads();
    for (int e = e0 + tid; e < e1; e += 256) {
        int s = src[e], d = dst[e];
        int bk = d >> 8;
        int pos = lbase[bk] + atomicAdd(&cnt[bk], 1);
        pairs[pos] = ((unsigned)(d & 255) << 17) | (unsigned)s;
    }
}

// One block per bucket. Computes its own compact base by reducing bcur fill
// levels (mkboff folded in, one fewer dispatch), then per-node count + LDS
// scan -> row_start/deg, then emits compact csr from the padded pairs window.
__global__ __launch_bounds__(256) void bucket_fill(
        const unsigned* __restrict__ pairs, const int* __restrict__ bcur,
        int* __restrict__ csr, int* __restrict__ row_start, int* __restrict__ deg) {
    __shared__ int cnt[256], sd[256], lcur[256];
    int b = blockIdx.x, tid = threadIdx.x;
    int pbase = b * BCAP;

    // base = sum_{i<b} (bcur[i] - i*BCAP)
    int psum = 0;
    for (int i = tid; i < b; i += 256) psum += bcur[i] - i * BCAP;
    sd[tid] = psum;
    __syncthreads();
    for (int st = 128; st > 0; st >>= 1) {
        if (tid < st) sd[tid] += sd[tid + st];
        __syncthreads();
    }
    int base = sd[0];
    int count = bcur[b] - b * BCAP;

    cnt[tid] = 0;
    __syncthreads();
    for (int i = tid; i < count; i += 256)
        atomicAdd(&cnt[pairs[pbase + i] >> 17], 1);
    __syncthreads();
    sd[tid] = cnt[tid];
    __syncthreads();
    for (int st = 1; st < 256; st <<= 1) {
        int t = (tid >= st) ? sd[tid - st] : 0;
        __syncthreads();
        sd[tid] += t;
        __syncthreads();
    }
    int excl = sd[tid] - cnt[tid];
    int node = b * 256 + tid;
    if (node < N_NODES_C) { row_start[node] = base + excl; deg[node] = cnt[tid]; }
    lcur[tid] = excl;
    __syncthreads();
    for (int i = tid; i < count; i += 256) {
        unsigned p = pairs[pbase + i];
        int pos = base + atomicAdd(&lcur[p >> 17], 1);
        csr[pos] = (int)(p & 0x1FFFFu);
    }
}

// ---------------------------------------------------------------------------
// Weight prep. Wt rows 0..127: L0 (K=256); 128..255: L1 (K=256);
// L2 compact at Wt+65536: 80 rows x K=128 (cols 0..39 = Ws2, 40..79 = Wn2).
__global__ void prep_weights(const void* Ws0, const void* bs0, const void* Wn0, const void* bn0,
                             const void* Ws1, const void* bs1, const void* Wn1, const void* bn1,
                             const void* Ws2, const void* bs2, const void* Wn2, const void* bn2,
                             unsigned short* __restrict__ Wt, float* __restrict__ bcat,
                             const int* __restrict__ gflag) {
    int gb = *gflag;
    int n = blockIdx.x;        // 0..335
    int k = threadIdx.x;       // 0..255
    if (n < 128) {
        float v = (k < 128) ? load1v(Ws0, (size_t)k * 128 + n, gb)
                            : load1v(Wn0, (size_t)(k - 128) * 128 + n, gb);
        Wt[(size_t)n * 256 + k] = f2bf(v);
        if (k == 0) bcat[n] = load1v(bs0, n, gb) + load1v(bn0, n, gb);
    } else if (n < 256) {
        int c = n - 128;
        float v = (k < 128) ? load1v(Ws1, (size_t)k * 128 + c, gb)
                            : load1v(Wn1, (size_t)(k - 128) * 128 + c, gb);
        Wt[(size_t)n * 256 + k] = f2bf(v);
        if (k == 0) bcat[n] = load1v(bs1, c, gb) + load1v(bn1, c, gb);
    } else {
        int c = n - 256;       // 0..79
        if (k < 128) {
            float v = (c < 40) ? load1v(Ws2, (size_t)k * 40 + c, gb)
                               : load1v(Wn2, (size_t)k * 40 + (c - 40), gb);
            Wt[65536 + (size_t)c * 128 + k] = f2bf(v);
        }
        if (k == 0) bcat[n] = (c < 40) ? load1v(bs2, c, gb) + load1v(bn2, c, gb) : 0.0f;
    }
}

// ---------------------------------------------------------------------------
// Gather-mean into X[:,128:256] (bf16). One node per 16-lane GROUP
// (4 nodes/wave); per-lane private accumulation; up to 8 row-loads in flight.
// Round-2 proven structure (the ~3.6 TB/s random-read ceiling).
__global__ __launch_bounds__(256) void gather_kernel(
        const void* __restrict__ hsrc, int src_stride,
        int src_mode, int copy_self,
        const int* __restrict__ csr,
        const int* __restrict__ row_start,
        const int* __restrict__ deg,
        unsigned short* __restrict__ X,
        const int* __restrict__ gflag) {
    int wave = threadIdx.x >> 6, lane = threadIdx.x & 63;
    int g = lane >> 4, sub = lane & 15;
    int srcLane = lane & 48;                       // g*16
    int node = blockIdx.x * 16 + wave * 4 + g;
    bool valid = node < N_NODES_C;
    int vnode = valid ? node : (N_NODES_C - 1);
    int start = row_start[vnode];
    int d = valid ? deg[vnode] : 0;
    const int* cp = csr + start;
    float inv = (d > 0) ? 1.0f / (float)d : 0.0f;
    int bf = (src_mode == 2) ? *gflag : src_mode;

    if (bf) {
        const unsigned short* hb = (const unsigned short*)hsrc;
        float a[8] = {0, 0, 0, 0, 0, 0, 0, 0};
        for (int base = 0; base < d; base += 16) {
            int n16 = min(d - base, 16);
            int idxr = cp[base + ((sub < n16) ? sub : 0)];
            int i = 0;
            for (; i + 8 <= n16; i += 8) {
                int nb0 = __shfl(idxr, srcLane + i + 0, 64);
                int nb1 = __shfl(idxr, srcLane + i + 1, 64);
                int nb2 = __shfl(idxr, srcLane + i + 2, 64);
                int nb3 = __shfl(idxr, srcLane + i + 3, 64);
                int nb4 = __shfl(idxr, srcLane + i + 4, 64);
                int nb5 = __shfl(idxr, srcLane + i + 5, 64);
                int nb6 = __shfl(idxr, srcLane + i + 6, 64);
                int nb7 = __shfl(idxr, srcLane + i + 7, 64);
                u32x4 r0 = *(const u32x4*)(hb + (size_t)nb0 * src_stride + sub * 8);
                u32x4 r1 = *(const u32x4*)(hb + (size_t)nb1 * src_stride + sub * 8);
                u32x4 r2 = *(const u32x4*)(hb + (size_t)nb2 * src_stride + sub * 8);
                u32x4 r3 = *(const u32x4*)(hb + (size_t)nb3 * src_stride + sub * 8);
                u32x4 r4 = *(const u32x4*)(hb + (size_t)nb4 * src_stride + sub * 8);
                u32x4 r5 = *(const u32x4*)(hb + (size_t)nb5 * src_stride + sub * 8);
                u32x4 r6 = *(const u32x4*)(hb + (size_t)nb6 * src_stride + sub * 8);
                u32x4 r7 = *(const u32x4*)(hb + (size_t)nb7 * src_stride + sub * 8);
                acc8(a, r0); acc8(a, r1); acc8(a, r2); acc8(a, r3);
                acc8(a, r4); acc8(a, r5); acc8(a, r6); acc8(a, r7);
            }
            for (; i + 4 <= n16; i += 4) {
                int nb0 = __shfl(idxr, srcLane + i + 0, 64);
                int nb1 = __shfl(idxr, srcLane + i + 1, 64);
                int nb2 = __shfl(idxr, srcLane + i + 2, 64);
                int nb3 = __shfl(idxr, srcLane + i + 3, 64);
                u32x4 r0 = *(const u32x4*)(hb + (size_t)nb0 * src_stride + sub * 8);
                u32x4 r1 = *(const u32x4*)(hb + (size_t)nb1 * src_stride + sub * 8);
                u32x4 r2 = *(const u32x4*)(hb + (size_t)nb2 * src_stride + sub * 8);
                u32x4 r3 = *(const u32x4*)(hb + (size_t)nb3 * src_stride + sub * 8);
                acc8(a, r0); acc8(a, r1); acc8(a, r2); acc8(a, r3);
            }
            for (; i < n16; ++i) {
                int nb = __shfl(idxr, srcLane + i, 64);
                u32x4 r = *(const u32x4*)(hb + (size_t)nb * src_stride + sub * 8);
                acc8(a, r);
            }
        }
        if (valid) {
            u32x4 o;
            o.x = (unsigned)f2bf(a[0] * inv) | ((unsigned)f2bf(a[1] * inv) << 16);
            o.y = (unsigned)f2bf(a[2] * inv) | ((unsigned)f2bf(a[3] * inv) << 16);
            o.z = (unsigned)f2bf(a[4] * inv) | ((unsigned)f2bf(a[5] * inv) << 16);
            o.w = (unsigned)f2bf(a[6] * inv) | ((unsigned)f2bf(a[7] * inv) << 16);
            *(u32x4*)(X + (size_t)node * 256 + 128 + sub * 8) = o;
            if (copy_self) {
                u32x4 raw = *(const u32x4*)(hb + (size_t)node * src_stride + sub * 8);
                *(u32x4*)(X + (size_t)node * 256 + sub * 8) = raw;
            }
        }
    } else {
        const float* hf = (const float*)hsrc;
        float a[8] = {0, 0, 0, 0, 0, 0, 0, 0};
        for (int base = 0; base < d; base += 16) {
            int n16 = min(d - base, 16);
            int idxr = cp[base + ((sub < n16) ? sub : 0)];
            int i = 0;
            for (; i + 4 <= n16; i += 4) {
                int nb0 = __shfl(idxr, srcLane + i + 0, 64);
                int nb1 = __shfl(idxr, srcLane + i + 1, 64);
                int nb2 = __shfl(idxr, srcLane + i + 2, 64);
                int nb3 = __shfl(idxr, srcLane + i + 3, 64);
                const float* p0 = hf + (size_t)nb0 * src_stride + sub * 4;
                const float* p1 = hf + (size_t)nb1 * src_stride + sub * 4;
                const float* p2 = hf + (size_t)nb2 * src_stride + sub * 4;
                const float* p3 = hf + (size_t)nb3 * src_stride + sub * 4;
                f32x4 a0 = *(const f32x4*)p0, b0 = *(const f32x4*)(p0 + 64);
                f32x4 a1 = *(const f32x4*)p1, b1 = *(const f32x4*)(p1 + 64);
                f32x4 a2 = *(const f32x4*)p2, b2 = *(const f32x4*)(p2 + 64);
                f32x4 a3 = *(const f32x4*)p3, b3 = *(const f32x4*)(p3 + 64);
#pragma unroll
                for (int k = 0; k < 4; ++k) {
                    a[k] += a0[k] + a1[k] + a2[k] + a3[k];
                    a[4 + k] += b0[k] + b1[k] + b2[k] + b3[k];
                }
            }
            for (; i < n16; ++i) {
                int nb = __shfl(idxr, srcLane + i, 64);
                const float* p0 = hf + (size_t)nb * src_stride + sub * 4;
                f32x4 a0 = *(const f32x4*)p0, b0 = *(const f32x4*)(p0 + 64);
#pragma unroll
                for (int k = 0; k < 4; ++k) { a[k] += a0[k]; a[4 + k] += b0[k]; }
            }
        }
        if (valid) {
            u16x4 oa = { f2bf(a[0] * inv), f2bf(a[1] * inv),
                         f2bf(a[2] * inv), f2bf(a[3] * inv) };
            u16x4 ob = { f2bf(a[4] * inv), f2bf(a[5] * inv),
                         f2bf(a[6] * inv), f2bf(a[7] * inv) };
            *(u16x4*)(X + (size_t)node * 256 + 128 + sub * 4) = oa;
            *(u16x4*)(X + (size_t)node * 256 + 128 + 64 + sub * 4) = ob;
            if (copy_self) {
                const float* sp = hf + (size_t)node * src_stride + sub * 4;
                f32x4 ra = *(const f32x4*)sp;
                f32x4 rb = *(const f32x4*)(sp + 64);
                u16x4 sa = { f2bf(ra.x), f2bf(ra.y), f2bf(ra.z), f2bf(ra.w) };
                u16x4 sb = { f2bf(rb.x), f2bf(rb.y), f2bf(rb.z), f2bf(rb.w) };
                *(u16x4*)(X + (size_t)node * 256 + sub * 4) = sa;
                *(u16x4*)(X + (size_t)node * 256 + 64 + sub * 4) = sb;
            }
        }
    }
}

// ---------------------------------------------------------------------------
// MFMA GEMM. DUAL=false: out[node][c] bf16, stride out_stride (layers 0/1).
// DUAL=true: cols 0..39 -> Zbuf (stride 64), cols 40..79 -> Ybuf (stride 64).
template <int NCT, int KT, int CHK, bool ACTNORM, bool DUAL>
__global__ __launch_bounds__(256) void mfma_gemm(
        const unsigned short* __restrict__ X, int astride,
        const u32x4* __restrict__ Wg,           // [NCT*16][CHK] 16B chunks
        const float* __restrict__ bias,         // [NCT*16]
        unsigned short* __restrict__ out, int out_stride,
        unsigned short* __restrict__ Ybuf, unsigned short* __restrict__ Zbuf,
        int n_nodes) {
    __shared__ u32x4 ldsW[NCT * 16 * CHK];
    int tid = threadIdx.x;
    for (int c = tid; c < NCT * 16 * CHK; c += 256) {
        int nrow = c / CHK, ch = c % CHK;
        ldsW[nrow * CHK + (ch ^ (nrow & 7))] = Wg[c];
    }
    __syncthreads();

    int wave = tid >> 6, lane = tid & 63;
    int quad = lane >> 4, sub = lane & 15;
    int mynode = blockIdx.x * 64 + wave * 16 + sub;
    int arow = (mynode < n_nodes) ? mynode : (n_nodes - 1);
    const unsigned short* ap = X + (size_t)arow * astride + quad * 8;

    f32x4 acc[NCT];
#pragma unroll
    for (int ct = 0; ct < NCT; ++ct) acc[ct] = (f32x4){0,0,0,0};

    short8 av = *(const short8*)ap;
#pragma unroll
    for (int kt = 0; kt < KT; ++kt) {
        short8 av_next = av;
        if (kt < KT - 1) av_next = *(const short8*)(ap + (kt + 1) * 32);
        int chunk = kt * 4 + quad;
#pragma unroll
        for (int ct = 0; ct < NCT; ++ct) {
            int ncol = ct * 16 + sub;
            union { u32x4 u; short8 s; } cv;
            cv.u = ldsW[ncol * CHK + (chunk ^ (ncol & 7))];
            acc[ct] = __builtin_amdgcn_mfma_f32_16x16x32_bf16(cv.s, av, acc[ct], 0, 0, 0);
        }
        av = av_next;
    }

    float ss = 0.0f;
#pragma unroll
    for (int ct = 0; ct < NCT; ++ct) {
        f32x4 b4 = *(const f32x4*)(bias + ct * 16 + quad * 4);
#pragma unroll
        for (int r = 0; r < 4; ++r) {
            float v = acc[ct][r] + b4[r];
            if (ACTNORM) { v = fmaxf(v, 0.0f); ss += v * v; }
            acc[ct][r] = v;
        }
    }
    float scale = 1.0f;
    if (ACTNORM) {
        ss += __shfl_xor(ss, 16, 64);
        ss += __shfl_xor(ss, 32, 64);
        scale = 1.0f / fmaxf(sqrtf(ss), 1e-12f);
    }
    if (mynode < n_nodes) {
#pragma unroll
        for (int ct = 0; ct < NCT; ++ct) {
            int c0 = ct * 16 + quad * 4;
            u16x4 o = { f2bf(acc[ct][0] * scale), f2bf(acc[ct][1] * scale),
                        f2bf(acc[ct][2] * scale), f2bf(acc[ct][3] * scale) };
            if (DUAL) {
                if (c0 < 40) *(u16x4*)(Zbuf + (size_t)mynode * 64 + c0) = o;
                else         *(u16x4*)(Ybuf + (size_t)mynode * 64 + (c0 - 40)) = o;
            } else {
                *(u16x4*)(out + (size_t)mynode * out_stride + c0) = o;
            }
        }
    }
}

// ---------------------------------------------------------------------------
// Layer-2 finish v2: out[n] = mean_{nb}(Y2[nb]) + Z2[n].
// v4-gather recipe: one node per 8-LANE group (8 nodes/wave), Y2 stride 64 so
// 8 lanes x 16B = one aligned 128B row; per-lane private accumulation (no
// cross-lane reduce); x8 row burst = up to 64 row-loads in flight per wave.
// Lanes 5..7 accumulate row padding and are discarded at the guarded write.
__global__ __launch_bounds__(256) void combine_kernel(
        const unsigned short* __restrict__ Y2,   // stride 64
        const unsigned short* __restrict__ Z2,   // stride 64
        const int* __restrict__ csr,
        const int* __restrict__ row_start,
        const int* __restrict__ deg,
        void* __restrict__ out,
        const int* __restrict__ gflag) {
    int wave = threadIdx.x >> 6, lane = threadIdx.x & 63;
    int grp = lane >> 3, sub = lane & 7;
    int grpLane = lane & 56;                      // grp*8
    int node = blockIdx.x * 32 + wave * 8 + grp;
    bool valid = node < N_NODES_C;
    int vnode = valid ? node : (N_NODES_C - 1);
    int start = row_start[vnode];
    int d = valid ? deg[vnode] : 0;
    const int* cp = csr + start;

    float a[8] = {0, 0, 0, 0, 0, 0, 0, 0};
    for (int base = 0; base < d; base += 8) {
        int n8 = min(d - base, 8);
        int idxr = cp[base + ((sub < n8) ? sub : 0)];
        if (n8 == 8) {
            int nb0 = __shfl(idxr, grpLane + 0, 64);
            int nb1 = __shfl(idxr, grpLane + 1, 64);
            int nb2 = __shfl(idxr, grpLane + 2, 64);
            int nb3 = __shfl(idxr, grpLane + 3, 64);
            int nb4 = __shfl(idxr, grpLane + 4, 64);
            int nb5 = __shfl(idxr, grpLane + 5, 64);
            int nb6 = __shfl(idxr, grpLane + 6, 64);
            int nb7 = __shfl(idxr, grpLane + 7, 64);
            u32x4 r0 = *(const u32x4*)(Y2 + (size_t)nb0 * 64 + sub * 8);
            u32x4 r1 = *(const u32x4*)(Y2 + (size_t)nb1 * 64 + sub * 8);
            u32x4 r2 = *(const u32x4*)(Y2 + (size_t)nb2 * 64 + sub * 8);
            u32x4 r3 = *(const u32x4*)(Y2 + (size_t)nb3 * 64 + sub * 8);
            u32x4 r4 = *(const u32x4*)(Y2 + (size_t)nb4 * 64 + sub * 8);
            u32x4 r5 = *(const u32x4*)(Y2 + (size_t)nb5 * 64 + sub * 8);
            u32x4 r6 = *(const u32x4*)(Y2 + (size_t)nb6 * 64 + sub * 8);
            u32x4 r7 = *(const u32x4*)(Y2 + (size_t)nb7 * 64 + sub * 8);
            acc8(a, r0); acc8(a, r1); acc8(a, r2); acc8(a, r3);
            acc8(a, r4); acc8(a, r5); acc8(a, r6); acc8(a, r7);
        } else {
            for (int j = 0; j < n8; ++j) {
                int nb = __shfl(idxr, grpLane + j, 64);
                u32x4 r = *(const u32x4*)(Y2 + (size_t)nb * 64 + sub * 8);
                acc8(a, r);
            }
        }
    }

    if (valid) {
        float inv = (d > 0) ? 1.0f / (float)d : 0.0f;
        u32x4 z = *(const u32x4*)(Z2 + (size_t)node * 64 + sub * 8);
        float v[8];
        v[0] = a[0] * inv + bf_lo(z.x); v[1] = a[1] * inv + bf_hi(z.x);
        v[2] = a[2] * inv + bf_lo(z.y); v[3] = a[3] * inv + bf_hi(z.y);
        v[4] = a[4] * inv + bf_lo(z.z); v[5] = a[5] * inv + bf_hi(z.z);
        v[6] = a[6] * inv + bf_lo(z.w); v[7] = a[7] * inv + bf_hi(z.w);
        if (sub < 5) {
            if (*gflag) {
                u32x4 o;
                o.x = (unsigned)f2bf(v[0]) | ((unsigned)f2bf(v[1]) << 16);
                o.y = (unsigned)f2bf(v[2]) | ((unsigned)f2bf(v[3]) << 16);
                o.z = (unsigned)f2bf(v[4]) | ((unsigned)f2bf(v[5]) << 16);
                o.w = (unsigned)f2bf(v[6]) | ((unsigned)f2bf(v[7]) << 16);
                *(u32x4*)((unsigned short*)out + (size_t)node * 40 + sub * 8) = o;
            } else {
                float* op = (float*)out + (size_t)node * 40 + sub * 8;
                f32x4 o0 = { v[0], v[1], v[2], v[3] };
                f32x4 o1 = { v[4], v[5], v[6], v[7] };
                *(f32x4*)op = o0;
                *(f32x4*)(op + 4) = o1;
            }
        }
    }
}

// ---------------------------------------------------------------------------
extern "C" void kernel_launch(void* const* d_in, const int* in_sizes, int n_in,
                              void* d_out, int out_size, void* d_ws, size_t ws_size,
                              hipStream_t stream) {
    const void* feats = d_in[0];
    const int*  src   = (const int*)d_in[1];
    const int*  dst   = (const int*)d_in[2];

    char* ws = (char*)d_ws;
    unsigned short* X0   = (unsigned short*)ws;                        // 51,200,000
    unsigned short* X1   = (unsigned short*)(ws + 51200000);           // 51,200,000
    unsigned short* Wt   = (unsigned short*)(ws + 102400000);          //   ~283,000
    float*          bcat = (float*)(ws + 102912000);                   //     1,344
    unsigned short* Y2   = (unsigned short*)(ws + 102916096);          // 12,800,000 (stride 64)
    unsigned short* Z2   = (unsigned short*)(ws + 115716096);          // 12,800,000 (stride 64)
    unsigned*       pairs= (unsigned*)(ws + 102916096);                // alias Y2 (pre-GEMM only), 7.2 MB
    int*  csr       = (int*)(ws + 128516096);                          //  6,400,000
    int*  row_start = (int*)(ws + 134916096);                          //    400,000
    int*  deg       = (int*)(ws + 135316096);                          //    400,000
    int*  bcur      = (int*)(ws + 135720192);                          // N_BUCK*4
    int*  gflag     = (int*)(ws + 135722240);

    // ---- dtype probe + bucket cursor init (no memsets needed) ----
    detect_init<<<1, 64, 0, stream>>>(feats, gflag, bcur);

    // ---- bucketed CSR build (mkboff folded into bucket_fill) ----
    partition2<<<PART_NB, 256, 0, stream>>>(src, dst, bcur, pairs);
    bucket_fill<<<N_BUCK, 256, 0, stream>>>(pairs, bcur, csr, row_start, deg);

    // ---- weights ----
    prep_weights<<<336, 256, 0, stream>>>(
        d_in[3], d_in[4], d_in[5], d_in[6],
        d_in[7], d_in[8], d_in[9], d_in[10],
        d_in[11], d_in[12], d_in[13], d_in[14], Wt, bcat, gflag);

    const int gblk = (N_NODES_C + 15) / 16;   // 4 nodes/wave, 16 nodes/block
    const int cblk = (N_NODES_C + 31) / 32;   // 8 nodes/wave, 32 nodes/block
    const int mblk = (N_NODES_C + 63) / 64;

    // layer 0: feats -> X0 = [self | mean] -> X1[:,0:128]
    gather_kernel<<<gblk, 256, 0, stream>>>(feats, 128, 2, 1, csr, row_start, deg, X0, gflag);
    mfma_gemm<8, 8, 32, true, false><<<mblk, 256, 0, stream>>>(
        X0, 256, (const u32x4*)Wt, bcat, X1, 256, nullptr, nullptr, N_NODES_C);

    // layer 1: X1 -> X0[:,0:128]
    gather_kernel<<<gblk, 256, 0, stream>>>(X1, 256, 1, 0, csr, row_start, deg, X1, gflag);
    mfma_gemm<8, 8, 32, true, false><<<mblk, 256, 0, stream>>>(
        X1, 256, (const u32x4*)(Wt + 128 * 256), bcat + 128, X0, 256, nullptr, nullptr, N_NODES_C);

    // layer 2 (transform-then-aggregate): h2 -> Y2 = h2@Wn2, Z2 = h2@Ws2 + b
    mfma_gemm<5, 4, 16, false, true><<<mblk, 256, 0, stream>>>(
        X0, 256, (const u32x4*)(Wt + 65536), bcat + 256, nullptr, 0, Y2, Z2, N_NODES_C);

    // out = mean(Y2[nbrs]) + Z2
    combine_kernel<<<cblk, 256, 0, stream>>>(Y2, Z2, csr, row_start, deg, d_out, gflag);
}

// Round 7
// 460.160 us; speedup vs baseline: 1.0949x; 1.0015x over previous
//
#include <hip/hip_runtime.h>
#include <hip/hip_bf16.h>

#define N_NODES_C 100000
#define N_EDGES_C 1600000
#define N_BUCK ((N_NODES_C + 255) / 256)   // 391
#define BCAP 4608                          // per-bucket capacity, mean 4092 + 8 sigma
#define PART_NB 160
#define PART_CHUNK ((N_EDGES_C + PART_NB - 1) / PART_NB)  // 10000

typedef __attribute__((ext_vector_type(8))) short          short8;   // 8 bf16
typedef __attribute__((ext_vector_type(4))) float          f32x4;
typedef __attribute__((ext_vector_type(4))) unsigned int   u32x4;
typedef __attribute__((ext_vector_type(4))) unsigned short u16x4;

// ---------------------------------------------------------------------------
__device__ inline float load1v(const void* p, size_t i, int bf) {
    return bf ? __bfloat162float(((const __hip_bfloat16*)p)[i])
              : ((const float*)p)[i];
}
__device__ inline unsigned short f2bf(float f) {
    __hip_bfloat16 h = __float2bfloat16(f);
    return *reinterpret_cast<unsigned short*>(&h);
}
__device__ inline float bf_lo(unsigned u) { return __uint_as_float(u << 16); }
__device__ inline float bf_hi(unsigned u) { return __uint_as_float(u & 0xffff0000u); }
__device__ inline void acc8(float* a, u32x4 r) {
    a[0] += bf_lo(r.x); a[1] += bf_hi(r.x);
    a[2] += bf_lo(r.y); a[3] += bf_hi(r.y);
    a[4] += bf_lo(r.z); a[5] += bf_hi(r.z);
    a[6] += bf_lo(r.w); a[7] += bf_hi(r.w);
}
// h2 LDS tile byte address: 256B rows, swizzled 16B chunk (XOR row&7).
__device__ inline int xaddr2(int l, int byteCol) {
    return l * 256 + ((((byteCol >> 4) ^ (l & 7)) << 4)) + (byteCol & 15);
}

// ---------------------------------------------------------------------------
// Dtype probe (gflag=1 iff float tensors are bf16) + bucket cursor init.
__global__ void detect_init(const void* __restrict__ feats, int* __restrict__ gflag,
                            int* __restrict__ bcur) {
    const unsigned short* u = (const unsigned short*)feats;
    int bad = 0;
    for (int i = threadIdx.x; i < 2048; i += 64) {
        unsigned e = (u[i] >> 7) & 0xFF;
        if (e >= 0xC0) bad++;
    }
#pragma unroll
    for (int off = 32; off > 0; off >>= 1) bad += __shfl_down(bad, off, 64);
    if (threadIdx.x == 0) *gflag = (bad == 0) ? 1 : 0;
    for (int b = threadIdx.x; b < N_BUCK; b += 64) bcur[b] = b * BCAP;
}

// ---------------------------------------------------------------------------
// Privatized two-pass partition into FIXED-CAP bucket slots.
__global__ __launch_bounds__(256) void partition2(
        const int* __restrict__ src, const int* __restrict__ dst,
        int* __restrict__ bcur, unsigned* __restrict__ pairs) {
    __shared__ int cnt[N_BUCK];
    __shared__ int lbase[N_BUCK];
    int tid = threadIdx.x;
    int e0 = blockIdx.x * PART_CHUNK;
    int e1 = min(e0 + PART_CHUNK, N_EDGES_C);
    for (int i = tid; i < N_BUCK; i += 256) cnt[i] = 0;
    __syncthreads();
    for (int e = e0 + tid; e < e1; e += 256)
        atomicAdd(&cnt[dst[e] >> 8], 1);
    __syncthreads();
    for (int i = tid; i < N_BUCK; i += 256) {
        int c = cnt[i];
        lbase[i] = c ? atomicAdd(&bcur[i], c) : 0;
        cnt[i] = 0;                       // reuse as local cursor
    }
    __syncthreads();
    for (int e = e0 + tid; e < e1; e += 256) {
        int s = src[e], d = dst[e];
        int bk = d >> 8;
        int pos = lbase[bk] + atomicAdd(&cnt[bk], 1);
        pairs[pos] = ((unsigned)(d & 255) << 17) | (unsigned)s;
    }
}

// One block per bucket. Computes its own compact base by reducing bcur fill
// levels (mkboff folded in), then per-node count + LDS scan -> row_start/deg,
// then emits compact csr from the padded pairs window.
__global__ __launch_bounds__(256) void bucket_fill(
        const unsigned* __restrict__ pairs, const int* __restrict__ bcur,
        int* __restrict__ csr, int* __restrict__ row_start, int* __restrict__ deg) {
    __shared__ int cnt[256], sd[256], lcur[256];
    int b = blockIdx.x, tid = threadIdx.x;
    int pbase = b * BCAP;

    // base = sum_{i<b} (bcur[i] - i*BCAP)
    int psum = 0;
    for (int i = tid; i < b; i += 256) psum += bcur[i] - i * BCAP;
    sd[tid] = psum;
    __syncthreads();
    for (int st = 128; st > 0; st >>= 1) {
        if (tid < st) sd[tid] += sd[tid + st];
        __syncthreads();
    }
    int base = sd[0];
    int count = bcur[b] - b * BCAP;

    cnt[tid] = 0;
    __syncthreads();
    for (int i = tid; i < count; i += 256)
        atomicAdd(&cnt[pairs[pbase + i] >> 17], 1);
    __syncthreads();
    sd[tid] = cnt[tid];
    __syncthreads();
    for (int st = 1; st < 256; st <<= 1) {
        int t = (tid >= st) ? sd[tid - st] : 0;
        __syncthreads();
        sd[tid] += t;
        __syncthreads();
    }
    int excl = sd[tid] - cnt[tid];
    int node = b * 256 + tid;
    if (node < N_NODES_C) { row_start[node] = base + excl; deg[node] = cnt[tid]; }
    lcur[tid] = excl;
    __syncthreads();
    for (int i = tid; i < count; i += 256) {
        unsigned p = pairs[pbase + i];
        int pos = base + atomicAdd(&lcur[p >> 17], 1);
        csr[pos] = (int)(p & 0x1FFFFu);
    }
}

// ---------------------------------------------------------------------------
// Weight prep. Wt rows 0..127: L0 (K=256); 128..255: L1 (K=256);
// L2 compact at Wt+65536: 80 rows x K=128 (cols 0..39 = Ws2, 40..79 = Wn2).
__global__ void prep_weights(const void* Ws0, const void* bs0, const void* Wn0, const void* bn0,
                             const void* Ws1, const void* bs1, const void* Wn1, const void* bn1,
                             const void* Ws2, const void* bs2, const void* Wn2, const void* bn2,
                             unsigned short* __restrict__ Wt, float* __restrict__ bcat,
                             const int* __restrict__ gflag) {
    int gb = *gflag;
    int n = blockIdx.x;        // 0..335
    int k = threadIdx.x;       // 0..255
    if (n < 128) {
        float v = (k < 128) ? load1v(Ws0, (size_t)k * 128 + n, gb)
                            : load1v(Wn0, (size_t)(k - 128) * 128 + n, gb);
        Wt[(size_t)n * 256 + k] = f2bf(v);
        if (k == 0) bcat[n] = load1v(bs0, n, gb) + load1v(bn0, n, gb);
    } else if (n < 256) {
        int c = n - 128;
        float v = (k < 128) ? load1v(Ws1, (size_t)k * 128 + c, gb)
                            : load1v(Wn1, (size_t)(k - 128) * 128 + c, gb);
        Wt[(size_t)n * 256 + k] = f2bf(v);
        if (k == 0) bcat[n] = load1v(bs1, c, gb) + load1v(bn1, c, gb);
    } else {
        int c = n - 256;       // 0..79
        if (k < 128) {
            float v = (c < 40) ? load1v(Ws2, (size_t)k * 40 + c, gb)
                               : load1v(Wn2, (size_t)k * 40 + (c - 40), gb);
            Wt[65536 + (size_t)c * 128 + k] = f2bf(v);
        }
        if (k == 0) bcat[n] = (c < 40) ? load1v(bs2, c, gb) + load1v(bn2, c, gb) : 0.0f;
    }
}

// ---------------------------------------------------------------------------
// Gather-mean into X[:,128:256] (bf16). One node per 16-lane GROUP
// (4 nodes/wave); per-lane private accumulation; up to 8 row-loads in flight.
// Round-2 proven structure (the ~3.6 TB/s random-read ceiling).
__global__ __launch_bounds__(256) void gather_kernel(
        const void* __restrict__ hsrc, int src_stride,
        int src_mode, int copy_self,
        const int* __restrict__ csr,
        const int* __restrict__ row_start,
        const int* __restrict__ deg,
        unsigned short* __restrict__ X,
        const int* __restrict__ gflag) {
    int wave = threadIdx.x >> 6, lane = threadIdx.x & 63;
    int g = lane >> 4, sub = lane & 15;
    int srcLane = lane & 48;                       // g*16
    int node = blockIdx.x * 16 + wave * 4 + g;
    bool valid = node < N_NODES_C;
    int vnode = valid ? node : (N_NODES_C - 1);
    int start = row_start[vnode];
    int d = valid ? deg[vnode] : 0;
    const int* cp = csr + start;
    float inv = (d > 0) ? 1.0f / (float)d : 0.0f;
    int bf = (src_mode == 2) ? *gflag : src_mode;

    if (bf) {
        const unsigned short* hb = (const unsigned short*)hsrc;
        float a[8] = {0, 0, 0, 0, 0, 0, 0, 0};
        for (int base = 0; base < d; base += 16) {
            int n16 = min(d - base, 16);
            int idxr = cp[base + ((sub < n16) ? sub : 0)];
            int i = 0;
            for (; i + 8 <= n16; i += 8) {
                int nb0 = __shfl(idxr, srcLane + i + 0, 64);
                int nb1 = __shfl(idxr, srcLane + i + 1, 64);
                int nb2 = __shfl(idxr, srcLane + i + 2, 64);
                int nb3 = __shfl(idxr, srcLane + i + 3, 64);
                int nb4 = __shfl(idxr, srcLane + i + 4, 64);
                int nb5 = __shfl(idxr, srcLane + i + 5, 64);
                int nb6 = __shfl(idxr, srcLane + i + 6, 64);
                int nb7 = __shfl(idxr, srcLane + i + 7, 64);
                u32x4 r0 = *(const u32x4*)(hb + (size_t)nb0 * src_stride + sub * 8);
                u32x4 r1 = *(const u32x4*)(hb + (size_t)nb1 * src_stride + sub * 8);
                u32x4 r2 = *(const u32x4*)(hb + (size_t)nb2 * src_stride + sub * 8);
                u32x4 r3 = *(const u32x4*)(hb + (size_t)nb3 * src_stride + sub * 8);
                u32x4 r4 = *(const u32x4*)(hb + (size_t)nb4 * src_stride + sub * 8);
                u32x4 r5 = *(const u32x4*)(hb + (size_t)nb5 * src_stride + sub * 8);
                u32x4 r6 = *(const u32x4*)(hb + (size_t)nb6 * src_stride + sub * 8);
                u32x4 r7 = *(const u32x4*)(hb + (size_t)nb7 * src_stride + sub * 8);
                acc8(a, r0); acc8(a, r1); acc8(a, r2); acc8(a, r3);
                acc8(a, r4); acc8(a, r5); acc8(a, r6); acc8(a, r7);
            }
            for (; i + 4 <= n16; i += 4) {
                int nb0 = __shfl(idxr, srcLane + i + 0, 64);
                int nb1 = __shfl(idxr, srcLane + i + 1, 64);
                int nb2 = __shfl(idxr, srcLane + i + 2, 64);
                int nb3 = __shfl(idxr, srcLane + i + 3, 64);
                u32x4 r0 = *(const u32x4*)(hb + (size_t)nb0 * src_stride + sub * 8);
                u32x4 r1 = *(const u32x4*)(hb + (size_t)nb1 * src_stride + sub * 8);
                u32x4 r2 = *(const u32x4*)(hb + (size_t)nb2 * src_stride + sub * 8);
                u32x4 r3 = *(const u32x4*)(hb + (size_t)nb3 * src_stride + sub * 8);
                acc8(a, r0); acc8(a, r1); acc8(a, r2); acc8(a, r3);
            }
            for (; i < n16; ++i) {
                int nb = __shfl(idxr, srcLane + i, 64);
                u32x4 r = *(const u32x4*)(hb + (size_t)nb * src_stride + sub * 8);
                acc8(a, r);
            }
        }
        if (valid) {
            u32x4 o;
            o.x = (unsigned)f2bf(a[0] * inv) | ((unsigned)f2bf(a[1] * inv) << 16);
            o.y = (unsigned)f2bf(a[2] * inv) | ((unsigned)f2bf(a[3] * inv) << 16);
            o.z = (unsigned)f2bf(a[4] * inv) | ((unsigned)f2bf(a[5] * inv) << 16);
            o.w = (unsigned)f2bf(a[6] * inv) | ((unsigned)f2bf(a[7] * inv) << 16);
            *(u32x4*)(X + (size_t)node * 256 + 128 + sub * 8) = o;
            if (copy_self) {
                u32x4 raw = *(const u32x4*)(hb + (size_t)node * src_stride + sub * 8);
                *(u32x4*)(X + (size_t)node * 256 + sub * 8) = raw;
            }
        }
    } else {
        const float* hf = (const float*)hsrc;
        float a[8] = {0, 0, 0, 0, 0, 0, 0, 0};
        for (int base = 0; base < d; base += 16) {
            int n16 = min(d - base, 16);
            int idxr = cp[base + ((sub < n16) ? sub : 0)];
            int i = 0;
            for (; i + 4 <= n16; i += 4) {
                int nb0 = __shfl(idxr, srcLane + i + 0, 64);
                int nb1 = __shfl(idxr, srcLane + i + 1, 64);
                int nb2 = __shfl(idxr, srcLane + i + 2, 64);
                int nb3 = __shfl(idxr, srcLane + i + 3, 64);
                const float* p0 = hf + (size_t)nb0 * src_stride + sub * 4;
                const float* p1 = hf + (size_t)nb1 * src_stride + sub * 4;
                const float* p2 = hf + (size_t)nb2 * src_stride + sub * 4;
                const float* p3 = hf + (size_t)nb3 * src_stride + sub * 4;
                f32x4 a0 = *(const f32x4*)p0, b0 = *(const f32x4*)(p0 + 64);
                f32x4 a1 = *(const f32x4*)p1, b1 = *(const f32x4*)(p1 + 64);
                f32x4 a2 = *(const f32x4*)p2, b2 = *(const f32x4*)(p2 + 64);
                f32x4 a3 = *(const f32x4*)p3, b3 = *(const f32x4*)(p3 + 64);
#pragma unroll
                for (int k = 0; k < 4; ++k) {
                    a[k] += a0[k] + a1[k] + a2[k] + a3[k];
                    a[4 + k] += b0[k] + b1[k] + b2[k] + b3[k];
                }
            }
            for (; i < n16; ++i) {
                int nb = __shfl(idxr, srcLane + i, 64);
                const float* p0 = hf + (size_t)nb * src_stride + sub * 4;
                f32x4 a0 = *(const f32x4*)p0, b0 = *(const f32x4*)(p0 + 64);
#pragma unroll
                for (int k = 0; k < 4; ++k) { a[k] += a0[k]; a[4 + k] += b0[k]; }
            }
        }
        if (valid) {
            u16x4 oa = { f2bf(a[0] * inv), f2bf(a[1] * inv),
                         f2bf(a[2] * inv), f2bf(a[3] * inv) };
            u16x4 ob = { f2bf(a[4] * inv), f2bf(a[5] * inv),
                         f2bf(a[6] * inv), f2bf(a[7] * inv) };
            *(u16x4*)(X + (size_t)node * 256 + 128 + sub * 4) = oa;
            *(u16x4*)(X + (size_t)node * 256 + 128 + 64 + sub * 4) = ob;
            if (copy_self) {
                const float* sp = hf + (size_t)node * src_stride + sub * 4;
                f32x4 ra = *(const f32x4*)sp;
                f32x4 rb = *(const f32x4*)(sp + 64);
                u16x4 sa = { f2bf(ra.x), f2bf(ra.y), f2bf(ra.z), f2bf(ra.w) };
                u16x4 sb = { f2bf(rb.x), f2bf(rb.y), f2bf(rb.z), f2bf(rb.w) };
                *(u16x4*)(X + (size_t)node * 256 + sub * 4) = sa;
                *(u16x4*)(X + (size_t)node * 256 + 64 + sub * 4) = sb;
            }
        }
    }
}

// ---------------------------------------------------------------------------
// MFMA GEMM (layer 0): out = actnorm(X @ W + b), stride-256 bf16 out.
template <int NCT, int KT, int CHK, bool ACTNORM>
__global__ __launch_bounds__(256) void mfma_gemm(
        const unsigned short* __restrict__ X, int astride,
        const u32x4* __restrict__ Wg,           // [NCT*16][CHK] 16B chunks
        const float* __restrict__ bias,         // [NCT*16]
        unsigned short* __restrict__ out, int out_stride,
        int n_nodes) {
    __shared__ u32x4 ldsW[NCT * 16 * CHK];
    int tid = threadIdx.x;
    for (int c = tid; c < NCT * 16 * CHK; c += 256) {
        int nrow = c / CHK, ch = c % CHK;
        ldsW[nrow * CHK + (ch ^ (nrow & 7))] = Wg[c];
    }
    __syncthreads();

    int wave = tid >> 6, lane = tid & 63;
    int quad = lane >> 4, sub = lane & 15;
    int mynode = blockIdx.x * 64 + wave * 16 + sub;
    int arow = (mynode < n_nodes) ? mynode : (n_nodes - 1);
    const unsigned short* ap = X + (size_t)arow * astride + quad * 8;

    f32x4 acc[NCT];
#pragma unroll
    for (int ct = 0; ct < NCT; ++ct) acc[ct] = (f32x4){0,0,0,0};

    short8 av = *(const short8*)ap;
#pragma unroll
    for (int kt = 0; kt < KT; ++kt) {
        short8 av_next = av;
        if (kt < KT - 1) av_next = *(const short8*)(ap + (kt + 1) * 32);
        int chunk = kt * 4 + quad;
#pragma unroll
        for (int ct = 0; ct < NCT; ++ct) {
            int ncol = ct * 16 + sub;
            union { u32x4 u; short8 s; } cv;
            cv.u = ldsW[ncol * CHK + (chunk ^ (ncol & 7))];
            acc[ct] = __builtin_amdgcn_mfma_f32_16x16x32_bf16(cv.s, av, acc[ct], 0, 0, 0);
        }
        av = av_next;
    }

    float ss = 0.0f;
#pragma unroll
    for (int ct = 0; ct < NCT; ++ct) {
        f32x4 b4 = *(const f32x4*)(bias + ct * 16 + quad * 4);
#pragma unroll
        for (int r = 0; r < 4; ++r) {
            float v = acc[ct][r] + b4[r];
            if (ACTNORM) { v = fmaxf(v, 0.0f); ss += v * v; }
            acc[ct][r] = v;
        }
    }
    float scale = 1.0f;
    if (ACTNORM) {
        ss += __shfl_xor(ss, 16, 64);
        ss += __shfl_xor(ss, 32, 64);
        scale = 1.0f / fmaxf(sqrtf(ss), 1e-12f);
    }
    if (mynode < n_nodes) {
#pragma unroll
        for (int ct = 0; ct < NCT; ++ct) {
            int c0 = ct * 16 + quad * 4;
            u16x4 o = { f2bf(acc[ct][0] * scale), f2bf(acc[ct][1] * scale),
                        f2bf(acc[ct][2] * scale), f2bf(acc[ct][3] * scale) };
            *(u16x4*)(out + (size_t)mynode * out_stride + c0) = o;
        }
    }
}

// ---------------------------------------------------------------------------
// FUSED layers 1+2: h2 = actnorm(X1 @ W1 + b1) kept in a 16 KB swizzled LDS
// tile (never written to HBM), then immediately Y2 = h2 @ Wn2, Z2 = h2 @ Ws2
// + b2 (W2 read direct from global, L1-resident). Deletes gemm2's 25.6 MB h2
// re-read + gemm1's 25.6 MB h2 write + one dispatch.
__global__ __launch_bounds__(256) void mfma_gemm_l12(
        const unsigned short* __restrict__ X, int astride,
        const u32x4* __restrict__ W1g,          // [128][32] 16B chunks (K=256)
        const float* __restrict__ b1,           // [128]
        const u32x4* __restrict__ W2g,          // [80][16] 16B chunks (K=128)
        const float* __restrict__ b2,           // [80]
        unsigned short* __restrict__ Ybuf,      // stride 64
        unsigned short* __restrict__ Zbuf,      // stride 64
        int n_nodes) {
    __shared__ u32x4 ldsW[128 * 16];            // 32 KB W1 K-half
    __shared__ u32x4 xt4[64 * 16];              // 16 KB h2 tile
    char* xt = (char*)xt4;

    int tid = threadIdx.x;
    int wave = tid >> 6, lane = tid & 63;
    int quad = lane >> 4, sub = lane & 15;
    int lrow = wave * 16 + sub;
    int mynode = blockIdx.x * 64 + lrow;
    int arow = (mynode < n_nodes) ? mynode : (n_nodes - 1);
    const unsigned short* ap = X + (size_t)arow * astride + quad * 8;

    // ---- phase 1: h2 = actnorm(X1 @ W1 + b1), W1 staged in two 32KB halves
    f32x4 acc[8];
#pragma unroll
    for (int ct = 0; ct < 8; ++ct) acc[ct] = (f32x4){0, 0, 0, 0};

    for (int half = 0; half < 2; ++half) {
        __syncthreads();
        for (int c = tid; c < 128 * 16; c += 256) {
            int nrow = c >> 4, ch = c & 15;
            ldsW[(nrow << 4) + (ch ^ (nrow & 7))] = W1g[nrow * 32 + half * 16 + ch];
        }
        __syncthreads();
#pragma unroll
        for (int kt4 = 0; kt4 < 4; ++kt4) {
            int kt = half * 4 + kt4;
            short8 av = *(const short8*)(ap + kt * 32);
            int chunk = kt4 * 4 + quad;
#pragma unroll
            for (int ct = 0; ct < 8; ++ct) {
                int ncol = ct * 16 + sub;
                union { u32x4 u; short8 s; } cv;
                cv.u = ldsW[(ncol << 4) + (chunk ^ (ncol & 7))];
                acc[ct] = __builtin_amdgcn_mfma_f32_16x16x32_bf16(cv.s, av, acc[ct], 0, 0, 0);
            }
        }
    }

    float ss = 0.0f;
#pragma unroll
    for (int ct = 0; ct < 8; ++ct) {
        f32x4 b4 = *(const f32x4*)(b1 + ct * 16 + quad * 4);
#pragma unroll
        for (int r = 0; r < 4; ++r) {
            float v = acc[ct][r] + b4[r];
            v = fmaxf(v, 0.0f); ss += v * v;
            acc[ct][r] = v;
        }
    }
    ss += __shfl_xor(ss, 16, 64);
    ss += __shfl_xor(ss, 32, 64);
    float scale = 1.0f / fmaxf(sqrtf(ss), 1e-12f);

    // h2 (bf16, same rounding as the old HBM round-trip) -> swizzled LDS tile
#pragma unroll
    for (int ct = 0; ct < 8; ++ct) {
        int byteCol = ct * 32 + quad * 8;
        u16x4 o = { f2bf(acc[ct][0] * scale), f2bf(acc[ct][1] * scale),
                    f2bf(acc[ct][2] * scale), f2bf(acc[ct][3] * scale) };
        *(u16x4*)(xt + xaddr2(lrow, byteCol)) = o;
    }
    __syncthreads();

    // ---- phase 2: Y2/Z2 = h2 @ [Ws2|Wn2] + b2 (K=128, 80 cols)
    f32x4 acc2[5];
#pragma unroll
    for (int ct = 0; ct < 5; ++ct) acc2[ct] = (f32x4){0, 0, 0, 0};

#pragma unroll
    for (int kt2 = 0; kt2 < 4; ++kt2) {
        short8 av;
        {
            union { u32x4 u; short8 s; } tv;
            tv.u = *(const u32x4*)(xt + xaddr2(lrow, kt2 * 64 + quad * 16));
            av = tv.s;
        }
#pragma unroll
        for (int ct = 0; ct < 5; ++ct) {
            int ncol = ct * 16 + sub;
            union { u32x4 u; short8 s; } cv;
            cv.u = W2g[(ncol << 4) + kt2 * 4 + quad];
            acc2[ct] = __builtin_amdgcn_mfma_f32_16x16x32_bf16(cv.s, av, acc2[ct], 0, 0, 0);
        }
    }

    if (mynode < n_nodes) {
#pragma unroll
        for (int ct = 0; ct < 5; ++ct) {
            f32x4 b4 = *(const f32x4*)(b2 + ct * 16 + quad * 4);
            int c0 = ct * 16 + quad * 4;
            u16x4 o = { f2bf(acc2[ct][0] + b4[0]), f2bf(acc2[ct][1] + b4[1]),
                        f2bf(acc2[ct][2] + b4[2]), f2bf(acc2[ct][3] + b4[3]) };
            if (c0 < 40) *(u16x4*)(Zbuf + (size_t)mynode * 64 + c0) = o;
            else         *(u16x4*)(Ybuf + (size_t)mynode * 64 + (c0 - 40)) = o;
        }
    }
}

// ---------------------------------------------------------------------------
// Layer-2 finish: out[n] = mean_{nb}(Y2[nb]) + Z2[n].
// One node per 8-lane group (8 nodes/wave), Y2 stride 64 (aligned 128B rows),
// per-lane private accumulation, x8 row burst. Lanes 5..7 accumulate row
// padding and are discarded at the guarded write.
__global__ __launch_bounds__(256) void combine_kernel(
        const unsigned short* __restrict__ Y2,   // stride 64
        const unsigned short* __restrict__ Z2,   // stride 64
        const int* __restrict__ csr,
        const int* __restrict__ row_start,
        const int* __restrict__ deg,
        void* __restrict__ out,
        const int* __restrict__ gflag) {
    int wave = threadIdx.x >> 6, lane = threadIdx.x & 63;
    int grp = lane >> 3, sub = lane & 7;
    int grpLane = lane & 56;                      // grp*8
    int node = blockIdx.x * 32 + wave * 8 + grp;
    bool valid = node < N_NODES_C;
    int vnode = valid ? node : (N_NODES_C - 1);
    int start = row_start[vnode];
    int d = valid ? deg[vnode] : 0;
    const int* cp = csr + start;

    float a[8] = {0, 0, 0, 0, 0, 0, 0, 0};
    for (int base = 0; base < d; base += 8) {
        int n8 = min(d - base, 8);
        int idxr = cp[base + ((sub < n8) ? sub : 0)];
        if (n8 == 8) {
            int nb0 = __shfl(idxr, grpLane + 0, 64);
            int nb1 = __shfl(idxr, grpLane + 1, 64);
            int nb2 = __shfl(idxr, grpLane + 2, 64);
            int nb3 = __shfl(idxr, grpLane + 3, 64);
            int nb4 = __shfl(idxr, grpLane + 4, 64);
            int nb5 = __shfl(idxr, grpLane + 5, 64);
            int nb6 = __shfl(idxr, grpLane + 6, 64);
            int nb7 = __shfl(idxr, grpLane + 7, 64);
            u32x4 r0 = *(const u32x4*)(Y2 + (size_t)nb0 * 64 + sub * 8);
            u32x4 r1 = *(const u32x4*)(Y2 + (size_t)nb1 * 64 + sub * 8);
            u32x4 r2 = *(const u32x4*)(Y2 + (size_t)nb2 * 64 + sub * 8);
            u32x4 r3 = *(const u32x4*)(Y2 + (size_t)nb3 * 64 + sub * 8);
            u32x4 r4 = *(const u32x4*)(Y2 + (size_t)nb4 * 64 + sub * 8);
            u32x4 r5 = *(const u32x4*)(Y2 + (size_t)nb5 * 64 + sub * 8);
            u32x4 r6 = *(const u32x4*)(Y2 + (size_t)nb6 * 64 + sub * 8);
            u32x4 r7 = *(const u32x4*)(Y2 + (size_t)nb7 * 64 + sub * 8);
            acc8(a, r0); acc8(a, r1); acc8(a, r2); acc8(a, r3);
            acc8(a, r4); acc8(a, r5); acc8(a, r6); acc8(a, r7);
        } else {
            for (int j = 0; j < n8; ++j) {
                int nb = __shfl(idxr, grpLane + j, 64);
                u32x4 r = *(const u32x4*)(Y2 + (size_t)nb * 64 + sub * 8);
                acc8(a, r);
            }
        }
    }

    if (valid) {
        float inv = (d > 0) ? 1.0f / (float)d : 0.0f;
        u32x4 z = *(const u32x4*)(Z2 + (size_t)node * 64 + sub * 8);
        float v[8];
        v[0] = a[0] * inv + bf_lo(z.x); v[1] = a[1] * inv + bf_hi(z.x);
        v[2] = a[2] * inv + bf_lo(z.y); v[3] = a[3] * inv + bf_hi(z.y);
        v[4] = a[4] * inv + bf_lo(z.z); v[5] = a[5] * inv + bf_hi(z.z);
        v[6] = a[6] * inv + bf_lo(z.w); v[7] = a[7] * inv + bf_hi(z.w);
        if (sub < 5) {
            if (*gflag) {
                u32x4 o;
                o.x = (unsigned)f2bf(v[0]) | ((unsigned)f2bf(v[1]) << 16);
                o.y = (unsigned)f2bf(v[2]) | ((unsigned)f2bf(v[3]) << 16);
                o.z = (unsigned)f2bf(v[4]) | ((unsigned)f2bf(v[5]) << 16);
                o.w = (unsigned)f2bf(v[6]) | ((unsigned)f2bf(v[7]) << 16);
                *(u32x4*)((unsigned short*)out + (size_t)node * 40 + sub * 8) = o;
            } else {
                float* op = (float*)out + (size_t)node * 40 + sub * 8;
                f32x4 o0 = { v[0], v[1], v[2], v[3] };
                f32x4 o1 = { v[4], v[5], v[6], v[7] };
                *(f32x4*)op = o0;
                *(f32x4*)(op + 4) = o1;
            }
        }
    }
}

// ---------------------------------------------------------------------------
extern "C" void kernel_launch(void* const* d_in, const int* in_sizes, int n_in,
                              void* d_out, int out_size, void* d_ws, size_t ws_size,
                              hipStream_t stream) {
    const void* feats = d_in[0];
    const int*  src   = (const int*)d_in[1];
    const int*  dst   = (const int*)d_in[2];

    char* ws = (char*)d_ws;
    unsigned short* X0   = (unsigned short*)ws;                        // 51,200,000
    unsigned short* X1   = (unsigned short*)(ws + 51200000);           // 51,200,000
    unsigned short* Wt   = (unsigned short*)(ws + 102400000);          //   ~283,000
    float*          bcat = (float*)(ws + 102912000);                   //     1,344
    unsigned short* Y2   = (unsigned short*)(ws + 102916096);          // 12,800,000 (stride 64)
    unsigned short* Z2   = (unsigned short*)(ws + 115716096);          // 12,800,000 (stride 64)
    unsigned*       pairs= (unsigned*)(ws + 102916096);                // alias Y2 (pre-GEMM only), 7.2 MB
    int*  csr       = (int*)(ws + 128516096);                          //  6,400,000
    int*  row_start = (int*)(ws + 134916096);                          //    400,000
    int*  deg       = (int*)(ws + 135316096);                          //    400,000
    int*  bcur      = (int*)(ws + 135720192);                          // N_BUCK*4
    int*  gflag     = (int*)(ws + 135722240);

    // ---- dtype probe + bucket cursor init (no memsets needed) ----
    detect_init<<<1, 64, 0, stream>>>(feats, gflag, bcur);

    // ---- bucketed CSR build (mkboff folded into bucket_fill) ----
    partition2<<<PART_NB, 256, 0, stream>>>(src, dst, bcur, pairs);
    bucket_fill<<<N_BUCK, 256, 0, stream>>>(pairs, bcur, csr, row_start, deg);

    // ---- weights ----
    prep_weights<<<336, 256, 0, stream>>>(
        d_in[3], d_in[4], d_in[5], d_in[6],
        d_in[7], d_in[8], d_in[9], d_in[10],
        d_in[11], d_in[12], d_in[13], d_in[14], Wt, bcat, gflag);

    const int gblk = (N_NODES_C + 15) / 16;   // 4 nodes/wave, 16 nodes/block
    const int cblk = (N_NODES_C + 31) / 32;   // 8 nodes/wave, 32 nodes/block
    const int mblk = (N_NODES_C + 63) / 64;

    // layer 0: feats -> X0 = [self | mean] -> X1[:,0:128]
    gather_kernel<<<gblk, 256, 0, stream>>>(feats, 128, 2, 1, csr, row_start, deg, X0, gflag);
    mfma_gemm<8, 8, 32, true><<<mblk, 256, 0, stream>>>(
        X0, 256, (const u32x4*)Wt, bcat, X1, 256, N_NODES_C);

    // layer 1 gather: X1 -> X1[:,128:256]
    gather_kernel<<<gblk, 256, 0, stream>>>(X1, 256, 1, 0, csr, row_start, deg, X1, gflag);

    // layers 1+2 fused: h2 stays in LDS; writes Y2 = h2@Wn2, Z2 = h2@Ws2 + b
    mfma_gemm_l12<<<mblk, 256, 0, stream>>>(
        X1, 256, (const u32x4*)(Wt + 128 * 256), bcat + 128,
        (const u32x4*)(Wt + 65536), bcat + 256, Y2, Z2, N_NODES_C);

    // out = mean(Y2[nbrs]) + Z2
    combine_kernel<<<cblk, 256, 0, stream>>>(Y2, Z2, csr, row_start, deg, d_out, gflag);
}